// Round 2
// baseline (439.646 us; speedup 1.0000x reference)
//
#include <hip/hip_runtime.h>
#include <hip/hip_bf16.h>
#include <math.h>

#define S_LEN 2048
#define DMODEL 1024
#define NHEAD 16
#define DHEAD 64
#define BATCH 4
#define MROWS (BATCH * S_LEN)  // 8192

typedef unsigned short u16;
typedef __attribute__((ext_vector_type(8))) short bf16x8;
typedef __attribute__((ext_vector_type(4))) float f32x4;

#define GLDS16(g, l)                                              \
  __builtin_amdgcn_global_load_lds(                               \
      (const __attribute__((address_space(1))) void*)(g),         \
      (__attribute__((address_space(3))) void*)(l), 16, 0, 0)

__device__ __forceinline__ u16 f2bf(float f) {
  unsigned u = __float_as_uint(f);
  u += 0x7fff + ((u >> 16) & 1);  // round-to-nearest-even
  return (u16)(u >> 16);
}

__device__ __forceinline__ f32x4 mfma16(bf16x8 a, bf16x8 b, f32x4 c) {
  return __builtin_amdgcn_mfma_f32_16x16x32_bf16(a, b, c, 0, 0, 0);
}

// ---------------- cast fp32 -> bf16 ----------------
__global__ __launch_bounds__(256) void castk(const float* __restrict__ in,
                                             u16* __restrict__ out, int n) {
  int i = (blockIdx.x * 256 + threadIdx.x) * 4;
  if (i >= n) return;
  f32x4 v = *(const f32x4*)(in + i);
  u16 a0 = f2bf(v[0]), a1 = f2bf(v[1]), a2 = f2bf(v[2]), a3 = f2bf(v[3]);
  out[i + 0] = a0; out[i + 1] = a1; out[i + 2] = a2; out[i + 3] = a3;
}

// ---------------- QKV projection GEMM ----------------
// C[m][n] = sum_k X[m][k] * W[n][k] + bias[n]; scatter to (b,h,s,d) bf16.
__global__ __launch_bounds__(256) void gemm_qkv(
    const u16* __restrict__ Xb,
    const u16* __restrict__ W0, const u16* __restrict__ W1, const u16* __restrict__ W2,
    const float* __restrict__ b0, const float* __restrict__ b1, const float* __restrict__ b2,
    u16* __restrict__ O0, u16* __restrict__ O1, u16* __restrict__ O2) {
  __shared__ u16 As[128 * 32];
  __shared__ u16 Bs[128 * 32];
  const int z = blockIdx.z;
  const u16* Wm = z == 0 ? W0 : (z == 1 ? W1 : W2);
  const float* bias = z == 0 ? b0 : (z == 1 ? b1 : b2);
  u16* Out = z == 0 ? O0 : (z == 1 ? O1 : O2);
  const int tid = threadIdx.x;
  const int wave = tid >> 6, lane = tid & 63, g = lane >> 4, c = lane & 15;
  const int wm = wave >> 1, wn = wave & 1;
  const int bm0 = blockIdx.y * 128, bn0 = blockIdx.x * 128;
  const int o = tid * 16;            // flat byte offset in 8KB tile
  const int row = o >> 6;            // 0..63
  const int kp8 = ((o >> 4) & 3) * 8;
  char* lA = (char*)As + wave * 1024;
  char* lB = (char*)Bs + wave * 1024;

  f32x4 acc[4][4];
#pragma unroll
  for (int m = 0; m < 4; ++m)
#pragma unroll
    for (int n = 0; n < 4; ++n) acc[m][n] = (f32x4){0.f, 0.f, 0.f, 0.f};

  for (int k0 = 0; k0 < DMODEL; k0 += 32) {
    __syncthreads();
    GLDS16(Xb + (size_t)(bm0 + row) * DMODEL + k0 + kp8, lA);
    GLDS16(Xb + (size_t)(bm0 + row + 64) * DMODEL + k0 + kp8, lA + 4096);
    GLDS16(Wm + (size_t)(bn0 + row) * DMODEL + k0 + kp8, lB);
    GLDS16(Wm + (size_t)(bn0 + row + 64) * DMODEL + k0 + kp8, lB + 4096);
    __syncthreads();
    bf16x8 af[4], bfr[4];
#pragma unroll
    for (int m = 0; m < 4; ++m)
      af[m] = *(const bf16x8*)(As + (wm * 64 + m * 16 + c) * 32 + g * 8);
#pragma unroll
    for (int n = 0; n < 4; ++n)
      bfr[n] = *(const bf16x8*)(Bs + (wn * 64 + n * 16 + c) * 32 + g * 8);
#pragma unroll
    for (int m = 0; m < 4; ++m)
#pragma unroll
      for (int n = 0; n < 4; ++n)
        acc[m][n] = mfma16(af[m], bfr[n], acc[m][n]);
  }
#pragma unroll
  for (int n = 0; n < 4; ++n) {
    const int coln = bn0 + wn * 64 + n * 16 + c;
    const float bn_ = bias[coln];
    const int h = coln >> 6, d = coln & 63;
#pragma unroll
    for (int m = 0; m < 4; ++m) {
#pragma unroll
      for (int r = 0; r < 4; ++r) {
        const int rowm = bm0 + wm * 64 + m * 16 + g * 4 + r;
        const int b_ = rowm >> 11, s_ = rowm & 2047;
        Out[(((size_t)(b_ * NHEAD + h) * S_LEN + s_) << 6) + d] =
            f2bf(acc[m][n][r] + bn_);
      }
    }
  }
}

// ---------------- output projection GEMM ----------------
__global__ __launch_bounds__(256) void gemm_out(
    const u16* __restrict__ Ab, const u16* __restrict__ Wm,
    const float* __restrict__ bias, float* __restrict__ Out) {
  __shared__ u16 As[128 * 32];
  __shared__ u16 Bs[128 * 32];
  const int tid = threadIdx.x;
  const int wave = tid >> 6, lane = tid & 63, g = lane >> 4, c = lane & 15;
  const int wm = wave >> 1, wn = wave & 1;
  const int bm0 = blockIdx.y * 128, bn0 = blockIdx.x * 128;
  const int o = tid * 16;
  const int row = o >> 6;
  const int kp8 = ((o >> 4) & 3) * 8;
  char* lA = (char*)As + wave * 1024;
  char* lB = (char*)Bs + wave * 1024;

  f32x4 acc[4][4];
#pragma unroll
  for (int m = 0; m < 4; ++m)
#pragma unroll
    for (int n = 0; n < 4; ++n) acc[m][n] = (f32x4){0.f, 0.f, 0.f, 0.f};

  for (int k0 = 0; k0 < DMODEL; k0 += 32) {
    __syncthreads();
    GLDS16(Ab + (size_t)(bm0 + row) * DMODEL + k0 + kp8, lA);
    GLDS16(Ab + (size_t)(bm0 + row + 64) * DMODEL + k0 + kp8, lA + 4096);
    GLDS16(Wm + (size_t)(bn0 + row) * DMODEL + k0 + kp8, lB);
    GLDS16(Wm + (size_t)(bn0 + row + 64) * DMODEL + k0 + kp8, lB + 4096);
    __syncthreads();
    bf16x8 af[4], bfr[4];
#pragma unroll
    for (int m = 0; m < 4; ++m)
      af[m] = *(const bf16x8*)(As + (wm * 64 + m * 16 + c) * 32 + g * 8);
#pragma unroll
    for (int n = 0; n < 4; ++n)
      bfr[n] = *(const bf16x8*)(Bs + (wn * 64 + n * 16 + c) * 32 + g * 8);
#pragma unroll
    for (int m = 0; m < 4; ++m)
#pragma unroll
      for (int n = 0; n < 4; ++n)
        acc[m][n] = mfma16(af[m], bfr[n], acc[m][n]);
  }
#pragma unroll
  for (int n = 0; n < 4; ++n) {
    const int coln = bn0 + wn * 64 + n * 16 + c;
    const float bn_ = bias[coln];
#pragma unroll
    for (int m = 0; m < 4; ++m) {
#pragma unroll
      for (int r = 0; r < 4; ++r) {
        const int rowm = bm0 + wm * 64 + m * 16 + g * 4 + r;
        Out[(size_t)rowm * DMODEL + coln] = acc[m][n][r] + bn_;
      }
    }
  }
}

// ---------------- causal flash attention ----------------
// block: (b,h) = blockIdx.y, q-tile of 64 = blockIdx.x*64; 4 waves x 16 q-rows.
__global__ __launch_bounds__(256) void attn_fwd(const u16* __restrict__ Qb,
                                                const u16* __restrict__ Kb,
                                                const u16* __restrict__ Vb,
                                                u16* __restrict__ AOb) {
  __shared__ u16 Vt[64 * 72];       // V transposed [d][kv], padded stride 72
  __shared__ u16 Pl[4][16 * 72];    // per-wave P tile [q][kv], padded stride 72
  const int tid = threadIdx.x;
  const int w = tid >> 6, lane = tid & 63, g = lane >> 4, c = lane & 15;
  const int bh = blockIdx.y;
  const int qb = blockIdx.x * 64;
  const size_t base = (size_t)bh * S_LEN * DHEAD;
  const int qrow = qb + w * 16 + c;
  const bf16x8 qf0 = *(const bf16x8*)(Qb + base + (size_t)qrow * 64 + g * 8);
  const bf16x8 qf1 = *(const bf16x8*)(Qb + base + (size_t)qrow * 64 + 32 + g * 8);

  f32x4 oacc[4];
  float mrow[4], lrow[4];
#pragma unroll
  for (int dt = 0; dt < 4; ++dt) oacc[dt] = (f32x4){0.f, 0.f, 0.f, 0.f};
#pragma unroll
  for (int r = 0; r < 4; ++r) { mrow[r] = -INFINITY; lrow[r] = 0.f; }

  const int nt = blockIdx.x + 1;
  for (int kt = 0; kt < nt; ++kt) {
    const int kv0 = kt * 64;
    __syncthreads();
    // stage V transposed: Vt[d][kv] = V[kv0+kv][d]
#pragma unroll
    for (int i = 0; i < 2; ++i) {
      const int idx8 = tid + i * 256;
      const int kvr = idx8 >> 3, d0 = (idx8 & 7) * 8;
      bf16x8 v = *(const bf16x8*)(Vb + base + (size_t)(kv0 + kvr) * 64 + d0);
#pragma unroll
      for (int j = 0; j < 8; ++j) Vt[(d0 + j) * 72 + kvr] = (u16)v[j];
    }
    // S = Q K^T  (K fragments straight from global, L2-resident)
    f32x4 s[4];
#pragma unroll
    for (int t = 0; t < 4; ++t) {
      f32x4 zacc = (f32x4){0.f, 0.f, 0.f, 0.f};
      const u16* kp = Kb + base + (size_t)(kv0 + t * 16 + c) * 64;
      bf16x8 kf0 = *(const bf16x8*)(kp + g * 8);
      bf16x8 kf1 = *(const bf16x8*)(kp + 32 + g * 8);
      zacc = mfma16(qf0, kf0, zacc);
      zacc = mfma16(qf1, kf1, zacc);
      s[t] = zacc;
    }
    const bool diag = (kt == nt - 1);
    float tmax[4] = {-1e30f, -1e30f, -1e30f, -1e30f};
#pragma unroll
    for (int t = 0; t < 4; ++t)
#pragma unroll
      for (int r = 0; r < 4; ++r) {
        float v = s[t][r] * 0.125f;  // 1/sqrt(64)
        if (diag && (kv0 + t * 16 + c) > (qb + w * 16 + g * 4 + r)) v = -1e30f;
        s[t][r] = v;
        tmax[r] = fmaxf(tmax[r], v);
      }
#pragma unroll
    for (int r = 0; r < 4; ++r) {
#pragma unroll
      for (int m_ = 1; m_ < 16; m_ <<= 1)
        tmax[r] = fmaxf(tmax[r], __shfl_xor(tmax[r], m_));
    }
    float rsum[4];
#pragma unroll
    for (int r = 0; r < 4; ++r) {
      const float mn = fmaxf(mrow[r], tmax[r]);
      const float sc = __expf(mrow[r] - mn);
      mrow[r] = mn;
      lrow[r] *= sc;
#pragma unroll
      for (int dt = 0; dt < 4; ++dt) oacc[dt][r] *= sc;  // per-element: reg r == row r
      rsum[r] = 0.f;
    }
#pragma unroll
    for (int t = 0; t < 4; ++t)
#pragma unroll
      for (int r = 0; r < 4; ++r) {
        const float p = __expf(s[t][r] - mrow[r]);
        rsum[r] += p;
        Pl[w][(g * 4 + r) * 72 + t * 16 + c] = f2bf(p);
      }
#pragma unroll
    for (int r = 0; r < 4; ++r) {
#pragma unroll
      for (int m_ = 1; m_ < 16; m_ <<= 1) rsum[r] += __shfl_xor(rsum[r], m_);
      lrow[r] += rsum[r];
    }
    __syncthreads();
    // O += P V
#pragma unroll
    for (int kk = 0; kk < 2; ++kk) {
      const bf16x8 pf = *(const bf16x8*)(&Pl[w][c * 72 + kk * 32 + g * 8]);
#pragma unroll
      for (int dt = 0; dt < 4; ++dt) {
        const bf16x8 vf = *(const bf16x8*)(&Vt[(dt * 16 + c) * 72 + kk * 32 + g * 8]);
        oacc[dt] = mfma16(pf, vf, oacc[dt]);
      }
    }
  }
  const int b_ = bh >> 4, h = bh & 15;
#pragma unroll
  for (int r = 0; r < 4; ++r) {
    const float inv = 1.0f / lrow[r];
    const int qg = qb + w * 16 + g * 4 + r;
    const size_t rowbase = ((size_t)(b_ * S_LEN + qg) * DMODEL) + h * 64;
#pragma unroll
    for (int dt = 0; dt < 4; ++dt)
      AOb[rowbase + dt * 16 + c] = f2bf(oacc[dt][r] * inv);
  }
}

extern "C" void kernel_launch(void* const* d_in, const int* in_sizes, int n_in,
                              void* d_out, int out_size, void* d_ws, size_t ws_size,
                              hipStream_t stream) {
  const float* x  = (const float*)d_in[0];
  const float* Wq = (const float*)d_in[1];
  const float* bq = (const float*)d_in[2];
  const float* Wk = (const float*)d_in[3];
  const float* bk = (const float*)d_in[4];
  const float* Wv = (const float*)d_in[5];
  const float* bv = (const float*)d_in[6];
  const float* Wo = (const float*)d_in[7];
  const float* bo = (const float*)d_in[8];
  float* out = (float*)d_out;
  char* ws = (char*)d_ws;

  const size_t MB = 1024 * 1024;
  u16* xb  = (u16*)(ws);              // 16 MB: x bf16 [8192][1024]
  u16* Wqb = (u16*)(ws + 16 * MB);    // 2 MB each
  u16* Wkb = (u16*)(ws + 18 * MB);
  u16* Wvb = (u16*)(ws + 20 * MB);
  u16* Wob = (u16*)(ws + 22 * MB);
  u16* Qb  = (u16*)(ws + 24 * MB);    // 16 MB (b,h,s,d)
  u16* Kb  = (u16*)(ws + 40 * MB);
  u16* Vb  = (u16*)(ws + 56 * MB);
  u16* AOb = (u16*)(ws + 72 * MB);    // 16 MB (b,s,h*d)

  castk<<<8192, 256, 0, stream>>>(x, xb, MROWS * DMODEL);
  castk<<<1024, 256, 0, stream>>>(Wq, Wqb, DMODEL * DMODEL);
  castk<<<1024, 256, 0, stream>>>(Wk, Wkb, DMODEL * DMODEL);
  castk<<<1024, 256, 0, stream>>>(Wv, Wvb, DMODEL * DMODEL);

  gemm_qkv<<<dim3(DMODEL / 128, MROWS / 128, 3), 256, 0, stream>>>(
      xb, Wqb, Wkb, Wvb, bq, bk, bv, Qb, Kb, Vb);

  castk<<<1024, 256, 0, stream>>>(Wo, Wob, DMODEL * DMODEL);

  attn_fwd<<<dim3(S_LEN / 64, BATCH * NHEAD), 256, 0, stream>>>(Qb, Kb, Vb, AOb);

  gemm_out<<<dim3(DMODEL / 128, MROWS / 128), 256, 0, stream>>>(AOb, Wob, bo, out);
}

// Round 3
// 272.688 us; speedup vs baseline: 1.6123x; 1.6123x over previous
//
#include <hip/hip_runtime.h>
#include <hip/hip_bf16.h>
#include <math.h>

#define S_LEN 2048
#define DMODEL 1024
#define NHEAD 16
#define DHEAD 64
#define BATCH 4
#define MROWS (BATCH * S_LEN)  // 8192

typedef unsigned short u16;
typedef __attribute__((ext_vector_type(4))) unsigned short u16x4;
typedef __attribute__((ext_vector_type(8))) short bf16x8;
typedef __attribute__((ext_vector_type(4))) float f32x4;

#define GLDS16(g, l)                                              \
  __builtin_amdgcn_global_load_lds(                               \
      (const __attribute__((address_space(1))) void*)(g),         \
      (__attribute__((address_space(3))) void*)(l), 16, 0, 0)

__device__ __forceinline__ u16 f2bf(float f) {
  unsigned u = __float_as_uint(f);
  u += 0x7fff + ((u >> 16) & 1);  // round-to-nearest-even
  return (u16)(u >> 16);
}

__device__ __forceinline__ f32x4 mfma16(bf16x8 a, bf16x8 b, f32x4 c) {
  return __builtin_amdgcn_mfma_f32_16x16x32_bf16(a, b, c, 0, 0, 0);
}

// ---------------- cast fp32 -> bf16 ----------------
__global__ __launch_bounds__(256) void castk(const float* __restrict__ in,
                                             u16* __restrict__ out, int n) {
  int i = (blockIdx.x * 256 + threadIdx.x) * 4;
  if (i >= n) return;
  f32x4 v = *(const f32x4*)(in + i);
  u16 a0 = f2bf(v[0]), a1 = f2bf(v[1]), a2 = f2bf(v[2]), a3 = f2bf(v[3]);
  out[i + 0] = a0; out[i + 1] = a1; out[i + 2] = a2; out[i + 3] = a3;
}

// ---------------- QKV projection GEMM ----------------
// C[m][n] = sum_k X[m][k] * W[n][k] + bias[n].
// z==0 -> Q (b,h,s,d); z==1 -> K (b,h,s,d); z==2 -> V^T (b,h,d,s).
__global__ __launch_bounds__(256) void gemm_qkv(
    const u16* __restrict__ Xb,
    const u16* __restrict__ W0, const u16* __restrict__ W1, const u16* __restrict__ W2,
    const float* __restrict__ b0, const float* __restrict__ b1, const float* __restrict__ b2,
    u16* __restrict__ O0, u16* __restrict__ O1, u16* __restrict__ O2) {
  __shared__ u16 As[128 * 32];
  __shared__ u16 Bs[128 * 32];
  const int z = blockIdx.z;
  const u16* Wm = z == 0 ? W0 : (z == 1 ? W1 : W2);
  const float* bias = z == 0 ? b0 : (z == 1 ? b1 : b2);
  u16* Out = z == 0 ? O0 : (z == 1 ? O1 : O2);
  const int tid = threadIdx.x;
  const int wave = tid >> 6, lane = tid & 63, g = lane >> 4, c = lane & 15;
  const int wm = wave >> 1, wn = wave & 1;
  const int bm0 = blockIdx.y * 128, bn0 = blockIdx.x * 128;
  const int o = tid * 16;            // flat byte offset in 8KB tile
  const int row = o >> 6;            // 0..63
  const int kp8 = ((o >> 4) & 3) * 8;
  char* lA = (char*)As + wave * 1024;
  char* lB = (char*)Bs + wave * 1024;

  f32x4 acc[4][4];
#pragma unroll
  for (int m = 0; m < 4; ++m)
#pragma unroll
    for (int n = 0; n < 4; ++n) acc[m][n] = (f32x4){0.f, 0.f, 0.f, 0.f};

  for (int k0 = 0; k0 < DMODEL; k0 += 32) {
    __syncthreads();
    GLDS16(Xb + (size_t)(bm0 + row) * DMODEL + k0 + kp8, lA);
    GLDS16(Xb + (size_t)(bm0 + row + 64) * DMODEL + k0 + kp8, lA + 4096);
    GLDS16(Wm + (size_t)(bn0 + row) * DMODEL + k0 + kp8, lB);
    GLDS16(Wm + (size_t)(bn0 + row + 64) * DMODEL + k0 + kp8, lB + 4096);
    __syncthreads();
    bf16x8 af[4], bfr[4];
#pragma unroll
    for (int m = 0; m < 4; ++m)
      af[m] = *(const bf16x8*)(As + (wm * 64 + m * 16 + c) * 32 + g * 8);
#pragma unroll
    for (int n = 0; n < 4; ++n)
      bfr[n] = *(const bf16x8*)(Bs + (wn * 64 + n * 16 + c) * 32 + g * 8);
#pragma unroll
    for (int m = 0; m < 4; ++m)
#pragma unroll
      for (int n = 0; n < 4; ++n)
        acc[m][n] = mfma16(af[m], bfr[n], acc[m][n]);
  }
  if (z < 2) {
    // Q/K: (b,h,s,d) scatter
#pragma unroll
    for (int n = 0; n < 4; ++n) {
      const int coln = bn0 + wn * 64 + n * 16 + c;
      const float bn_ = bias[coln];
      const int h = coln >> 6, d = coln & 63;
#pragma unroll
      for (int m = 0; m < 4; ++m) {
#pragma unroll
        for (int r = 0; r < 4; ++r) {
          const int rowm = bm0 + wm * 64 + m * 16 + g * 4 + r;
          const int b_ = rowm >> 11, s_ = rowm & 2047;
          Out[(((size_t)(b_ * NHEAD + h) * S_LEN + s_) << 6) + d] =
              f2bf(acc[m][n][r] + bn_);
        }
      }
    }
  } else {
    // V^T: (b,h,d,s) — pack the 4 consecutive-s values into one 8B store
#pragma unroll
    for (int n = 0; n < 4; ++n) {
      const int coln = bn0 + wn * 64 + n * 16 + c;
      const float bn_ = bias[coln];
      const int h = coln >> 6, d = coln & 63;
#pragma unroll
      for (int m = 0; m < 4; ++m) {
        const int row0 = bm0 + wm * 64 + m * 16 + g * 4;
        const int b_ = row0 >> 11, s_ = row0 & 2047;
        u16x4 pk;
#pragma unroll
        for (int r = 0; r < 4; ++r) pk[r] = f2bf(acc[m][n][r] + bn_);
        *(u16x4*)(Out + ((size_t)(b_ * NHEAD + h) * DHEAD + d) * S_LEN + s_) = pk;
      }
    }
  }
}

// ---------------- output projection GEMM ----------------
__global__ __launch_bounds__(256) void gemm_out(
    const u16* __restrict__ Ab, const u16* __restrict__ Wm,
    const float* __restrict__ bias, float* __restrict__ Out) {
  __shared__ u16 As[128 * 32];
  __shared__ u16 Bs[128 * 32];
  const int tid = threadIdx.x;
  const int wave = tid >> 6, lane = tid & 63, g = lane >> 4, c = lane & 15;
  const int wm = wave >> 1, wn = wave & 1;
  const int bm0 = blockIdx.y * 128, bn0 = blockIdx.x * 128;
  const int o = tid * 16;
  const int row = o >> 6;
  const int kp8 = ((o >> 4) & 3) * 8;
  char* lA = (char*)As + wave * 1024;
  char* lB = (char*)Bs + wave * 1024;

  f32x4 acc[4][4];
#pragma unroll
  for (int m = 0; m < 4; ++m)
#pragma unroll
    for (int n = 0; n < 4; ++n) acc[m][n] = (f32x4){0.f, 0.f, 0.f, 0.f};

  for (int k0 = 0; k0 < DMODEL; k0 += 32) {
    __syncthreads();
    GLDS16(Ab + (size_t)(bm0 + row) * DMODEL + k0 + kp8, lA);
    GLDS16(Ab + (size_t)(bm0 + row + 64) * DMODEL + k0 + kp8, lA + 4096);
    GLDS16(Wm + (size_t)(bn0 + row) * DMODEL + k0 + kp8, lB);
    GLDS16(Wm + (size_t)(bn0 + row + 64) * DMODEL + k0 + kp8, lB + 4096);
    __syncthreads();
    bf16x8 af[4], bfr[4];
#pragma unroll
    for (int m = 0; m < 4; ++m)
      af[m] = *(const bf16x8*)(As + (wm * 64 + m * 16 + c) * 32 + g * 8);
#pragma unroll
    for (int n = 0; n < 4; ++n)
      bfr[n] = *(const bf16x8*)(Bs + (wn * 64 + n * 16 + c) * 32 + g * 8);
#pragma unroll
    for (int m = 0; m < 4; ++m)
#pragma unroll
      for (int n = 0; n < 4; ++n)
        acc[m][n] = mfma16(af[m], bfr[n], acc[m][n]);
  }
#pragma unroll
  for (int n = 0; n < 4; ++n) {
    const int coln = bn0 + wn * 64 + n * 16 + c;
    const float bn_ = bias[coln];
#pragma unroll
    for (int m = 0; m < 4; ++m) {
#pragma unroll
      for (int r = 0; r < 4; ++r) {
        const int rowm = bm0 + wm * 64 + m * 16 + g * 4 + r;
        Out[(size_t)rowm * DMODEL + coln] = acc[m][n][r] + bn_;
      }
    }
  }
}

// ---------------- causal flash attention ----------------
// 1-D grid of 2048 blocks; XCD-chunked remap so each XCD owns 8 heads
// (4MB K+V = one L2); qt reversed so heavy blocks launch first.
// 4 waves x 16 q-rows. K and V^T tiles staged in LDS via global_load_lds
// with XOR chunk swizzle (linear dest + pre-swizzled source + swizzled read).
__global__ __launch_bounds__(256) void attn_fwd(const u16* __restrict__ Qb,
                                                const u16* __restrict__ Kb,
                                                const u16* __restrict__ VTb,
                                                u16* __restrict__ AOb) {
  __shared__ u16 Kt[64 * 64];       // K tile [kv][d], swizzled chunks
  __shared__ u16 Vt[64 * 64];       // V^T tile [d][kv], swizzled chunks
  __shared__ u16 Pl[4][16 * 72];    // per-wave P tile [q][kv], padded stride 72
  const int tid = threadIdx.x;
  const int w = tid >> 6, lane = tid & 63, g = lane >> 4, c = lane & 15;
  const int flat = blockIdx.x;
  const int wg = (flat & 7) * 256 + (flat >> 3);  // XCD-chunked remap
  const int bh = wg >> 5;
  const int qt = 31 - (wg & 31);                  // heavy tiles first
  const int qb = qt * 64;
  const size_t base = (size_t)bh * (S_LEN * DHEAD);  // same stride for K and VT
  const int qrow = qb + w * 16 + c;
  const bf16x8 qf0 = *(const bf16x8*)(Qb + base + (size_t)qrow * 64 + g * 8);
  const bf16x8 qf1 = *(const bf16x8*)(Qb + base + (size_t)qrow * 64 + 32 + g * 8);

  // staging chunk index per thread (2 calls x 256 chunks of 16B per matrix)
  const int ci0 = w * 64 + lane;

  f32x4 oacc[4];
  float mrow[4], lrow[4];
#pragma unroll
  for (int dt = 0; dt < 4; ++dt) oacc[dt] = (f32x4){0.f, 0.f, 0.f, 0.f};
#pragma unroll
  for (int r = 0; r < 4; ++r) { mrow[r] = -INFINITY; lrow[r] = 0.f; }

  const int nt = qt + 1;
  for (int kt = 0; kt < nt; ++kt) {
    const int kv0 = kt * 64;
    __syncthreads();  // prev tile's LDS reads done before overwrite
#pragma unroll
    for (int call = 0; call < 2; ++call) {
      const int ci = call * 256 + ci0;
      const int row = ci >> 3;                  // 0..63
      const int colg = (ci & 7) ^ (row & 7);    // inverse-swizzled source chunk
      GLDS16(Kb + base + (size_t)(kv0 + row) * 64 + colg * 8,
             (char*)Kt + (call * 256 + w * 64) * 16);
      GLDS16(VTb + base + (size_t)row * S_LEN + kv0 + colg * 8,
             (char*)Vt + (call * 256 + w * 64) * 16);
    }
    __syncthreads();  // compiler drains vmcnt before barrier -> tiles ready
    // S = Q K^T from swizzled LDS
    f32x4 s[4];
#pragma unroll
    for (int t = 0; t < 4; ++t) {
      const int krow = t * 16 + c;
      const char* kbase = (const char*)Kt + krow * 128;
      bf16x8 kf0 = *(const bf16x8*)(kbase + ((g ^ (krow & 7)) * 16));
      bf16x8 kf1 = *(const bf16x8*)(kbase + (((4 + g) ^ (krow & 7)) * 16));
      f32x4 zacc = (f32x4){0.f, 0.f, 0.f, 0.f};
      zacc = mfma16(qf0, kf0, zacc);
      zacc = mfma16(qf1, kf1, zacc);
      s[t] = zacc;
    }
    const bool diag = (kt == nt - 1);
    float tmax[4] = {-1e30f, -1e30f, -1e30f, -1e30f};
#pragma unroll
    for (int t = 0; t < 4; ++t)
#pragma unroll
      for (int r = 0; r < 4; ++r) {
        float v = s[t][r] * 0.125f;  // 1/sqrt(64)
        if (diag && (kv0 + t * 16 + c) > (qb + w * 16 + g * 4 + r)) v = -1e30f;
        s[t][r] = v;
        tmax[r] = fmaxf(tmax[r], v);
      }
#pragma unroll
    for (int r = 0; r < 4; ++r) {
#pragma unroll
      for (int m_ = 1; m_ < 16; m_ <<= 1)
        tmax[r] = fmaxf(tmax[r], __shfl_xor(tmax[r], m_));
    }
    float rsum[4];
#pragma unroll
    for (int r = 0; r < 4; ++r) {
      const float mn = fmaxf(mrow[r], tmax[r]);
      const float sc = __expf(mrow[r] - mn);
      mrow[r] = mn;
      lrow[r] *= sc;
#pragma unroll
      for (int dt = 0; dt < 4; ++dt) oacc[dt][r] *= sc;  // per-element: reg r == row r
      rsum[r] = 0.f;
    }
#pragma unroll
    for (int t = 0; t < 4; ++t)
#pragma unroll
      for (int r = 0; r < 4; ++r) {
        const float p = __expf(s[t][r] - mrow[r]);
        rsum[r] += p;
        Pl[w][(g * 4 + r) * 72 + t * 16 + c] = f2bf(p);
      }
#pragma unroll
    for (int r = 0; r < 4; ++r) {
#pragma unroll
      for (int m_ = 1; m_ < 16; m_ <<= 1) rsum[r] += __shfl_xor(rsum[r], m_);
      lrow[r] += rsum[r];
    }
    __syncthreads();  // P visible (wave-local but keep waves in phase)
    // O += P V from swizzled V^T tile
#pragma unroll
    for (int kk = 0; kk < 2; ++kk) {
      const bf16x8 pf = *(const bf16x8*)(&Pl[w][c * 72 + kk * 32 + g * 8]);
#pragma unroll
      for (int dt = 0; dt < 4; ++dt) {
        const int vrow = dt * 16 + c;
        const bf16x8 vf = *(const bf16x8*)((const char*)Vt + vrow * 128 +
                                           (((kk * 4 + g) ^ (vrow & 7)) * 16));
        oacc[dt] = mfma16(pf, vf, oacc[dt]);
      }
    }
  }
  const int b_ = bh >> 4, h = bh & 15;
#pragma unroll
  for (int r = 0; r < 4; ++r) {
    const float inv = 1.0f / lrow[r];
    const int qg = qb + w * 16 + g * 4 + r;
    const size_t rowbase = ((size_t)(b_ * S_LEN + qg) * DMODEL) + h * 64;
#pragma unroll
    for (int dt = 0; dt < 4; ++dt)
      AOb[rowbase + dt * 16 + c] = f2bf(oacc[dt][r] * inv);
  }
}

extern "C" void kernel_launch(void* const* d_in, const int* in_sizes, int n_in,
                              void* d_out, int out_size, void* d_ws, size_t ws_size,
                              hipStream_t stream) {
  const float* x  = (const float*)d_in[0];
  const float* Wq = (const float*)d_in[1];
  const float* bq = (const float*)d_in[2];
  const float* Wk = (const float*)d_in[3];
  const float* bk = (const float*)d_in[4];
  const float* Wv = (const float*)d_in[5];
  const float* bv = (const float*)d_in[6];
  const float* Wo = (const float*)d_in[7];
  const float* bo = (const float*)d_in[8];
  float* out = (float*)d_out;
  char* ws = (char*)d_ws;

  const size_t MB = 1024 * 1024;
  u16* xb  = (u16*)(ws);              // 16 MB: x bf16 [8192][1024]
  u16* Wqb = (u16*)(ws + 16 * MB);    // 2 MB each
  u16* Wkb = (u16*)(ws + 18 * MB);
  u16* Wvb = (u16*)(ws + 20 * MB);
  u16* Wob = (u16*)(ws + 22 * MB);
  u16* Qb  = (u16*)(ws + 24 * MB);    // 16 MB (b,h,s,d)
  u16* Kb  = (u16*)(ws + 40 * MB);    // 16 MB (b,h,s,d)
  u16* VTb = (u16*)(ws + 56 * MB);    // 16 MB (b,h,d,s)  <-- transposed V
  u16* AOb = (u16*)(ws + 72 * MB);    // 16 MB (b,s,h*d)

  castk<<<8192, 256, 0, stream>>>(x, xb, MROWS * DMODEL);
  castk<<<1024, 256, 0, stream>>>(Wq, Wqb, DMODEL * DMODEL);
  castk<<<1024, 256, 0, stream>>>(Wk, Wkb, DMODEL * DMODEL);
  castk<<<1024, 256, 0, stream>>>(Wv, Wvb, DMODEL * DMODEL);

  gemm_qkv<<<dim3(DMODEL / 128, MROWS / 128, 3), 256, 0, stream>>>(
      xb, Wqb, Wkb, Wvb, bq, bk, bv, Qb, Kb, VTb);

  castk<<<1024, 256, 0, stream>>>(Wo, Wob, DMODEL * DMODEL);

  attn_fwd<<<2048, 256, 0, stream>>>(Qb, Kb, VTb, AOb);

  gemm_out<<<dim3(DMODEL / 128, MROWS / 128), 256, 0, stream>>>(AOb, Wob, bo, out);
}

// Round 5
// 209.477 us; speedup vs baseline: 2.0988x; 1.3018x over previous
//
#include <hip/hip_runtime.h>
#include <hip/hip_bf16.h>
#include <math.h>

#define S_LEN 2048
#define DMODEL 1024
#define NHEAD 16
#define DHEAD 64
#define BATCH 4
#define MROWS (BATCH * S_LEN)  // 8192

typedef unsigned short u16;
typedef __attribute__((ext_vector_type(4))) unsigned short u16x4;
typedef __attribute__((ext_vector_type(2))) unsigned u32x2;
typedef __attribute__((ext_vector_type(8))) short bf16x8;
typedef __attribute__((ext_vector_type(4))) float f32x4;

#define GLDS16(g, l)                                              \
  __builtin_amdgcn_global_load_lds(                               \
      (const __attribute__((address_space(1))) void*)(g),         \
      (__attribute__((address_space(3))) void*)(l), 16, 0, 0)

__device__ __forceinline__ u16 f2bf(float f) {
  unsigned u = __float_as_uint(f);
  u += 0x7fff + ((u >> 16) & 1);  // round-to-nearest-even
  return (u16)(u >> 16);
}

__device__ __forceinline__ f32x4 mfma16(bf16x8 a, bf16x8 b, f32x4 c) {
  return __builtin_amdgcn_mfma_f32_16x16x32_bf16(a, b, c, 0, 0, 0);
}

// ---------------- cast fp32 -> bf16 ----------------
__global__ __launch_bounds__(256) void castk(const float* __restrict__ in,
                                             u16* __restrict__ out, int n) {
  int i = (blockIdx.x * 256 + threadIdx.x) * 4;
  if (i >= n) return;
  f32x4 v = *(const f32x4*)(in + i);
  u16 a0 = f2bf(v[0]), a1 = f2bf(v[1]), a2 = f2bf(v[2]), a3 = f2bf(v[3]);
  out[i + 0] = a0; out[i + 1] = a1; out[i + 2] = a2; out[i + 3] = a3;
}

// ---------------- QKV projection GEMM ----------------
// C[m][n] = sum_k X[m][k] * W[n][k] + bias[n].
// z==0 -> Q (b,h,s,d) pre-scaled by 1/sqrt(64); z==1 -> K (b,h,s,d); z==2 -> V^T (b,h,d,s).
__global__ __launch_bounds__(256) void gemm_qkv(
    const u16* __restrict__ Xb,
    const u16* __restrict__ W0, const u16* __restrict__ W1, const u16* __restrict__ W2,
    const float* __restrict__ b0, const float* __restrict__ b1, const float* __restrict__ b2,
    u16* __restrict__ O0, u16* __restrict__ O1, u16* __restrict__ O2) {
  __shared__ u16 As[128 * 32];
  __shared__ u16 Bs[128 * 32];
  const int z = blockIdx.z;
  const u16* Wm = z == 0 ? W0 : (z == 1 ? W1 : W2);
  const float* bias = z == 0 ? b0 : (z == 1 ? b1 : b2);
  u16* Out = z == 0 ? O0 : (z == 1 ? O1 : O2);
  const float qs = (z == 0) ? 0.125f : 1.0f;  // fold 1/sqrt(D_HEAD) into Q
  const int tid = threadIdx.x;
  const int wave = tid >> 6, lane = tid & 63, g = lane >> 4, c = lane & 15;
  const int wm = wave >> 1, wn = wave & 1;
  const int bm0 = blockIdx.y * 128, bn0 = blockIdx.x * 128;
  const int o = tid * 16;            // flat byte offset in 8KB tile
  const int row = o >> 6;            // 0..63
  const int kp8 = ((o >> 4) & 3) * 8;
  char* lA = (char*)As + wave * 1024;
  char* lB = (char*)Bs + wave * 1024;

  f32x4 acc[4][4];
#pragma unroll
  for (int m = 0; m < 4; ++m)
#pragma unroll
    for (int n = 0; n < 4; ++n) acc[m][n] = (f32x4){0.f, 0.f, 0.f, 0.f};

  for (int k0 = 0; k0 < DMODEL; k0 += 32) {
    __syncthreads();
    GLDS16(Xb + (size_t)(bm0 + row) * DMODEL + k0 + kp8, lA);
    GLDS16(Xb + (size_t)(bm0 + row + 64) * DMODEL + k0 + kp8, lA + 4096);
    GLDS16(Wm + (size_t)(bn0 + row) * DMODEL + k0 + kp8, lB);
    GLDS16(Wm + (size_t)(bn0 + row + 64) * DMODEL + k0 + kp8, lB + 4096);
    __syncthreads();
    bf16x8 af[4], bfr[4];
#pragma unroll
    for (int m = 0; m < 4; ++m)
      af[m] = *(const bf16x8*)(As + (wm * 64 + m * 16 + c) * 32 + g * 8);
#pragma unroll
    for (int n = 0; n < 4; ++n)
      bfr[n] = *(const bf16x8*)(Bs + (wn * 64 + n * 16 + c) * 32 + g * 8);
#pragma unroll
    for (int m = 0; m < 4; ++m)
#pragma unroll
      for (int n = 0; n < 4; ++n)
        acc[m][n] = mfma16(af[m], bfr[n], acc[m][n]);
  }
  if (z < 2) {
    // Q/K: (b,h,s,d) scatter
#pragma unroll
    for (int n = 0; n < 4; ++n) {
      const int coln = bn0 + wn * 64 + n * 16 + c;
      const float bn_ = bias[coln];
      const int h = coln >> 6, d = coln & 63;
#pragma unroll
      for (int m = 0; m < 4; ++m) {
#pragma unroll
        for (int r = 0; r < 4; ++r) {
          const int rowm = bm0 + wm * 64 + m * 16 + g * 4 + r;
          const int b_ = rowm >> 11, s_ = rowm & 2047;
          Out[(((size_t)(b_ * NHEAD + h) * S_LEN + s_) << 6) + d] =
              f2bf((acc[m][n][r] + bn_) * qs);
        }
      }
    }
  } else {
    // V^T: (b,h,d,s) — pack the 4 consecutive-s values into one 8B store
#pragma unroll
    for (int n = 0; n < 4; ++n) {
      const int coln = bn0 + wn * 64 + n * 16 + c;
      const float bn_ = bias[coln];
      const int h = coln >> 6, d = coln & 63;
#pragma unroll
      for (int m = 0; m < 4; ++m) {
        const int row0 = bm0 + wm * 64 + m * 16 + g * 4;
        const int b_ = row0 >> 11, s_ = row0 & 2047;
        u16x4 pk;
#pragma unroll
        for (int r = 0; r < 4; ++r) pk[r] = f2bf(acc[m][n][r] + bn_);
        *(u16x4*)(Out + ((size_t)(b_ * NHEAD + h) * DHEAD + d) * S_LEN + s_) = pk;
      }
    }
  }
}

// ---------------- output projection GEMM ----------------
__global__ __launch_bounds__(256) void gemm_out(
    const u16* __restrict__ Ab, const u16* __restrict__ Wm,
    const float* __restrict__ bias, float* __restrict__ Out) {
  __shared__ u16 As[128 * 32];
  __shared__ u16 Bs[128 * 32];
  const int tid = threadIdx.x;
  const int wave = tid >> 6, lane = tid & 63, g = lane >> 4, c = lane & 15;
  const int wm = wave >> 1, wn = wave & 1;
  const int bm0 = blockIdx.y * 128, bn0 = blockIdx.x * 128;
  const int o = tid * 16;
  const int row = o >> 6;
  const int kp8 = ((o >> 4) & 3) * 8;
  char* lA = (char*)As + wave * 1024;
  char* lB = (char*)Bs + wave * 1024;

  f32x4 acc[4][4];
#pragma unroll
  for (int m = 0; m < 4; ++m)
#pragma unroll
    for (int n = 0; n < 4; ++n) acc[m][n] = (f32x4){0.f, 0.f, 0.f, 0.f};

  for (int k0 = 0; k0 < DMODEL; k0 += 32) {
    __syncthreads();
    GLDS16(Ab + (size_t)(bm0 + row) * DMODEL + k0 + kp8, lA);
    GLDS16(Ab + (size_t)(bm0 + row + 64) * DMODEL + k0 + kp8, lA + 4096);
    GLDS16(Wm + (size_t)(bn0 + row) * DMODEL + k0 + kp8, lB);
    GLDS16(Wm + (size_t)(bn0 + row + 64) * DMODEL + k0 + kp8, lB + 4096);
    __syncthreads();
    bf16x8 af[4], bfr[4];
#pragma unroll
    for (int m = 0; m < 4; ++m)
      af[m] = *(const bf16x8*)(As + (wm * 64 + m * 16 + c) * 32 + g * 8);
#pragma unroll
    for (int n = 0; n < 4; ++n)
      bfr[n] = *(const bf16x8*)(Bs + (wn * 64 + n * 16 + c) * 32 + g * 8);
#pragma unroll
    for (int m = 0; m < 4; ++m)
#pragma unroll
      for (int n = 0; n < 4; ++n)
        acc[m][n] = mfma16(af[m], bfr[n], acc[m][n]);
  }
#pragma unroll
  for (int n = 0; n < 4; ++n) {
    const int coln = bn0 + wn * 64 + n * 16 + c;
    const float bn_ = bias[coln];
#pragma unroll
    for (int m = 0; m < 4; ++m) {
#pragma unroll
      for (int r = 0; r < 4; ++r) {
        const int rowm = bm0 + wm * 64 + m * 16 + g * 4 + r;
        Out[(size_t)rowm * DMODEL + coln] = acc[m][n][r] + bn_;
      }
    }
  }
}

// ---------------- causal flash attention (swapped-operand, in-register softmax) ----------------
// grid 1024: 64 (b,h) x 16 pairs; each block does q-tiles {31-p, p} (33 tile-steps, balanced).
// 4 waves x 16 q-rows. S^T = mfma(K,Q): lane owns q=c's scores for kv = 16t+4g+r.
// PV swapped: O^T = mfma(V^T, P^T); P^T transported through a wave-local LDS
// buffer Pl[w][q=c][kv] (u32-packed bf16 pairs, stride 36 u32) — no cross-wave
// sharing, no barrier; compiler inserts lgkmcnt for the same-object LDS dep.
__global__ __launch_bounds__(256) void attn_fwd(const u16* __restrict__ Qb,
                                                const u16* __restrict__ Kb,
                                                const u16* __restrict__ VTb,
                                                u16* __restrict__ AOb) {
  __shared__ u16 Kt[64 * 64];       // K tile [kv][d], swizzled chunks
  __shared__ u16 Vt[64 * 64];       // V^T tile [d][kv], swizzled chunks
  __shared__ unsigned Pl[4][16 * 36];  // per-wave P^T: row q=c (stride 36 u32 = 144B)
  const int tid = threadIdx.x;
  const int w = tid >> 6, lane = tid & 63, g = lane >> 4, c = lane & 15;
  const int flat = blockIdx.x;
  const int wg = (flat & 7) * 128 + (flat >> 3);  // XCD-chunked remap (8 heads/XCD)
  const int bh = wg >> 4;
  const int pr = wg & 15;
  const size_t base = (size_t)bh * (S_LEN * DHEAD);  // same stride for K and VT
  const int b_ = bh >> 4, h = bh & 15;
  const int ci0 = w * 64 + lane;    // staging chunk index

#pragma unroll
  for (int pass = 0; pass < 2; ++pass) {
    const int qt = pass ? pr : (31 - pr);
    const int qb = qt * 64;
    const int q = qb + w * 16 + c;   // this lane's q-row
    const bf16x8 qf0 = *(const bf16x8*)(Qb + base + (size_t)q * 64 + g * 8);
    const bf16x8 qf1 = *(const bf16x8*)(Qb + base + (size_t)q * 64 + 32 + g * 8);

    f32x4 oacc[4];
#pragma unroll
    for (int dt = 0; dt < 4; ++dt) oacc[dt] = (f32x4){0.f, 0.f, 0.f, 0.f};
    float m = -30000.f, l = 0.f;

    const int nt = qt + 1;
    for (int kt = 0; kt < nt; ++kt) {
      const int kv0 = kt * 64;
      __syncthreads();  // prev tile's LDS reads done before overwrite
#pragma unroll
      for (int call = 0; call < 2; ++call) {
        const int ci = call * 256 + ci0;
        const int row = ci >> 3;                  // 0..63
        const int colg = (ci & 7) ^ (row & 7);    // inverse-swizzled source chunk
        GLDS16(Kb + base + (size_t)(kv0 + row) * 64 + colg * 8,
               (char*)Kt + (call * 256 + w * 64) * 16);
        GLDS16(VTb + base + (size_t)row * S_LEN + kv0 + colg * 8,
               (char*)Vt + (call * 256 + w * 64) * 16);
      }
      __syncthreads();  // tiles ready (vmcnt drained at barrier)

      // S^T = K Q^T from swizzled LDS: s[t][r] = S[kv=kv0+16t+4g+r][q]
      f32x4 s[4];
#pragma unroll
      for (int t = 0; t < 4; ++t) {
        const int krow = t * 16 + c;
        const char* kbase = (const char*)Kt + krow * 128;
        bf16x8 kf0 = *(const bf16x8*)(kbase + ((g ^ (krow & 7)) * 16));
        bf16x8 kf1 = *(const bf16x8*)(kbase + (((4 + g) ^ (krow & 7)) * 16));
        f32x4 zacc = (f32x4){0.f, 0.f, 0.f, 0.f};
        zacc = mfma16(kf0, qf0, zacc);
        zacc = mfma16(kf1, qf1, zacc);
        s[t] = zacc;
      }
      if (kt == nt - 1) {  // diagonal tile only: causal mask
#pragma unroll
        for (int t = 0; t < 4; ++t)
#pragma unroll
          for (int r = 0; r < 4; ++r)
            if (kv0 + t * 16 + 4 * g + r > q) s[t][r] = -30000.f;
      }
      // in-register row max (16 values) + 2-step cross-g reduce
      float pm = s[0][0];
#pragma unroll
      for (int t = 0; t < 4; ++t)
#pragma unroll
        for (int r = 0; r < 4; ++r) pm = fmaxf(pm, s[t][r]);
      pm = fmaxf(pm, __shfl_xor(pm, 16));
      pm = fmaxf(pm, __shfl_xor(pm, 32));
      const float mn = fmaxf(m, pm);
      const float sc = __expf(m - mn);
      l *= sc;
#pragma unroll
      for (int dt = 0; dt < 4; ++dt) oacc[dt] *= sc;
      m = mn;
      float rs = 0.f;
#pragma unroll
      for (int t = 0; t < 4; ++t) {
        float p0 = __expf(s[t][0] - m), p1 = __expf(s[t][1] - m);
        float p2 = __expf(s[t][2] - m), p3 = __expf(s[t][3] - m);
        rs += (p0 + p1) + (p2 + p3);
        // P^T[q=c][kv = 16t+4g+0..3] as two packed u32 (one 8B store)
        u32x2 pk2;
        pk2[0] = (unsigned)f2bf(p0) | ((unsigned)f2bf(p1) << 16);
        pk2[1] = (unsigned)f2bf(p2) | ((unsigned)f2bf(p3) << 16);
        *(u32x2*)&Pl[w][c * 36 + t * 8 + g * 2] = pk2;
      }
      rs += __shfl_xor(rs, 16);
      rs += __shfl_xor(rs, 32);
      l += rs;

      // O^T += V^T P^T : P^T B-frag read back from wave-local LDS
#pragma unroll
      for (int kk = 0; kk < 2; ++kk) {
        const bf16x8 pb = *(const bf16x8*)&Pl[w][c * 36 + kk * 16 + g * 4];
#pragma unroll
        for (int dt = 0; dt < 4; ++dt) {
          const int vrow = dt * 16 + c;
          const bf16x8 vf = *(const bf16x8*)((const char*)Vt + vrow * 128 +
                                             (((kk * 4 + g) ^ (vrow & 7)) * 16));
          oacc[dt] = mfma16(vf, pb, oacc[dt]);
        }
      }
    }
    // epilogue: lane owns O[q][d = dt*16 + 4g + 0..3] -> 8B packed stores
    const float inv = 1.0f / l;
    const size_t rowbase = ((size_t)(b_ * S_LEN + q) * DMODEL) + h * 64;
#pragma unroll
    for (int dt = 0; dt < 4; ++dt) {
      u16x4 pk4;
#pragma unroll
      for (int r = 0; r < 4; ++r) pk4[r] = f2bf(oacc[dt][r] * inv);
      *(u16x4*)(AOb + rowbase + dt * 16 + 4 * g) = pk4;
    }
  }
}

extern "C" void kernel_launch(void* const* d_in, const int* in_sizes, int n_in,
                              void* d_out, int out_size, void* d_ws, size_t ws_size,
                              hipStream_t stream) {
  const float* x  = (const float*)d_in[0];
  const float* Wq = (const float*)d_in[1];
  const float* bq = (const float*)d_in[2];
  const float* Wk = (const float*)d_in[3];
  const float* bk = (const float*)d_in[4];
  const float* Wv = (const float*)d_in[5];
  const float* bv = (const float*)d_in[6];
  const float* Wo = (const float*)d_in[7];
  const float* bo = (const float*)d_in[8];
  float* out = (float*)d_out;
  char* ws = (char*)d_ws;

  const size_t MB = 1024 * 1024;
  u16* xb  = (u16*)(ws);              // 16 MB: x bf16 [8192][1024]
  u16* Wqb = (u16*)(ws + 16 * MB);    // 2 MB each
  u16* Wkb = (u16*)(ws + 18 * MB);
  u16* Wvb = (u16*)(ws + 20 * MB);
  u16* Wob = (u16*)(ws + 22 * MB);
  u16* Qb  = (u16*)(ws + 24 * MB);    // 16 MB (b,h,s,d), pre-scaled by 0.125
  u16* Kb  = (u16*)(ws + 40 * MB);    // 16 MB (b,h,s,d)
  u16* VTb = (u16*)(ws + 56 * MB);    // 16 MB (b,h,d,s)
  u16* AOb = (u16*)(ws + 72 * MB);    // 16 MB (b,s,h*d)

  castk<<<8192, 256, 0, stream>>>(x, xb, MROWS * DMODEL);
  castk<<<1024, 256, 0, stream>>>(Wq, Wqb, DMODEL * DMODEL);
  castk<<<1024, 256, 0, stream>>>(Wk, Wkb, DMODEL * DMODEL);
  castk<<<1024, 256, 0, stream>>>(Wv, Wvb, DMODEL * DMODEL);

  gemm_qkv<<<dim3(DMODEL / 128, MROWS / 128, 3), 256, 0, stream>>>(
      xb, Wqb, Wkb, Wvb, bq, bk, bv, Qb, Kb, VTb);

  castk<<<1024, 256, 0, stream>>>(Wo, Wob, DMODEL * DMODEL);

  attn_fwd<<<1024, 256, 0, stream>>>(Qb, Kb, VTb, AOb);

  gemm_out<<<dim3(DMODEL / 128, MROWS / 128), 256, 0, stream>>>(AOb, Wob, bo, out);
}

// Round 6
// 200.666 us; speedup vs baseline: 2.1909x; 1.0439x over previous
//
#include <hip/hip_runtime.h>
#include <hip/hip_bf16.h>
#include <math.h>

#define S_LEN 2048
#define DMODEL 1024
#define NHEAD 16
#define DHEAD 64
#define BATCH 4
#define MROWS (BATCH * S_LEN)  // 8192

typedef unsigned short u16;
typedef __attribute__((ext_vector_type(4))) unsigned short u16x4;
typedef __attribute__((ext_vector_type(2))) unsigned u32x2;
typedef __attribute__((ext_vector_type(8))) short bf16x8;
typedef __attribute__((ext_vector_type(4))) float f32x4;

#define GLDS16(g, l)                                              \
  __builtin_amdgcn_global_load_lds(                               \
      (const __attribute__((address_space(1))) void*)(g),         \
      (__attribute__((address_space(3))) void*)(l), 16, 0, 0)

__device__ __forceinline__ u16 f2bf(float f) {
  unsigned u = __float_as_uint(f);
  u += 0x7fff + ((u >> 16) & 1);  // round-to-nearest-even
  return (u16)(u >> 16);
}

__device__ __forceinline__ float exp2v(float x) {  // raw v_exp_f32 (base-2)
  float r;
  asm("v_exp_f32 %0, %1" : "=v"(r) : "v"(x));
  return r;
}

__device__ __forceinline__ f32x4 mfma16(bf16x8 a, bf16x8 b, f32x4 c) {
  return __builtin_amdgcn_mfma_f32_16x16x32_bf16(a, b, c, 0, 0, 0);
}

// ---------------- cast fp32 -> bf16 ----------------
__global__ __launch_bounds__(256) void castk(const float* __restrict__ in,
                                             u16* __restrict__ out, int n) {
  int i = (blockIdx.x * 256 + threadIdx.x) * 4;
  if (i >= n) return;
  f32x4 v = *(const f32x4*)(in + i);
  u16 a0 = f2bf(v[0]), a1 = f2bf(v[1]), a2 = f2bf(v[2]), a3 = f2bf(v[3]);
  out[i + 0] = a0; out[i + 1] = a1; out[i + 2] = a2; out[i + 3] = a3;
}

// ---------------- QKV projection GEMM ----------------
// C[m][n] = sum_k X[m][k] * W[n][k] + bias[n].
// z==0 -> Q (b,h,s,d) pre-scaled by log2(e)/sqrt(64); z==1 -> K; z==2 -> V^T (b,h,d,s).
__global__ __launch_bounds__(256) void gemm_qkv(
    const u16* __restrict__ Xb,
    const u16* __restrict__ W0, const u16* __restrict__ W1, const u16* __restrict__ W2,
    const float* __restrict__ b0, const float* __restrict__ b1, const float* __restrict__ b2,
    u16* __restrict__ O0, u16* __restrict__ O1, u16* __restrict__ O2) {
  __shared__ u16 As[128 * 32];
  __shared__ u16 Bs[128 * 32];
  const int z = blockIdx.z;
  const u16* Wm = z == 0 ? W0 : (z == 1 ? W1 : W2);
  const float* bias = z == 0 ? b0 : (z == 1 ? b1 : b2);
  u16* Out = z == 0 ? O0 : (z == 1 ? O1 : O2);
  // Q pre-scale: (1/sqrt(64)) * log2(e), so attn scores are in log2 units
  const float qs = (z == 0) ? 0.18033688011112042f : 1.0f;
  const int tid = threadIdx.x;
  const int wave = tid >> 6, lane = tid & 63, g = lane >> 4, c = lane & 15;
  const int wm = wave >> 1, wn = wave & 1;
  const int bm0 = blockIdx.y * 128, bn0 = blockIdx.x * 128;
  const int o = tid * 16;            // flat byte offset in 8KB tile
  const int row = o >> 6;            // 0..63
  const int kp8 = ((o >> 4) & 3) * 8;
  char* lA = (char*)As + wave * 1024;
  char* lB = (char*)Bs + wave * 1024;

  f32x4 acc[4][4];
#pragma unroll
  for (int m = 0; m < 4; ++m)
#pragma unroll
    for (int n = 0; n < 4; ++n) acc[m][n] = (f32x4){0.f, 0.f, 0.f, 0.f};

  for (int k0 = 0; k0 < DMODEL; k0 += 32) {
    __syncthreads();
    GLDS16(Xb + (size_t)(bm0 + row) * DMODEL + k0 + kp8, lA);
    GLDS16(Xb + (size_t)(bm0 + row + 64) * DMODEL + k0 + kp8, lA + 4096);
    GLDS16(Wm + (size_t)(bn0 + row) * DMODEL + k0 + kp8, lB);
    GLDS16(Wm + (size_t)(bn0 + row + 64) * DMODEL + k0 + kp8, lB + 4096);
    __syncthreads();
    bf16x8 af[4], bfr[4];
#pragma unroll
    for (int m = 0; m < 4; ++m)
      af[m] = *(const bf16x8*)(As + (wm * 64 + m * 16 + c) * 32 + g * 8);
#pragma unroll
    for (int n = 0; n < 4; ++n)
      bfr[n] = *(const bf16x8*)(Bs + (wn * 64 + n * 16 + c) * 32 + g * 8);
#pragma unroll
    for (int m = 0; m < 4; ++m)
#pragma unroll
      for (int n = 0; n < 4; ++n)
        acc[m][n] = mfma16(af[m], bfr[n], acc[m][n]);
  }
  if (z < 2) {
    // Q/K: (b,h,s,d) scatter
#pragma unroll
    for (int n = 0; n < 4; ++n) {
      const int coln = bn0 + wn * 64 + n * 16 + c;
      const float bn_ = bias[coln];
      const int h = coln >> 6, d = coln & 63;
#pragma unroll
      for (int m = 0; m < 4; ++m) {
#pragma unroll
        for (int r = 0; r < 4; ++r) {
          const int rowm = bm0 + wm * 64 + m * 16 + g * 4 + r;
          const int b_ = rowm >> 11, s_ = rowm & 2047;
          Out[(((size_t)(b_ * NHEAD + h) * S_LEN + s_) << 6) + d] =
              f2bf((acc[m][n][r] + bn_) * qs);
        }
      }
    }
  } else {
    // V^T: (b,h,d,s) — pack the 4 consecutive-s values into one 8B store
#pragma unroll
    for (int n = 0; n < 4; ++n) {
      const int coln = bn0 + wn * 64 + n * 16 + c;
      const float bn_ = bias[coln];
      const int h = coln >> 6, d = coln & 63;
#pragma unroll
      for (int m = 0; m < 4; ++m) {
        const int row0 = bm0 + wm * 64 + m * 16 + g * 4;
        const int b_ = row0 >> 11, s_ = row0 & 2047;
        u16x4 pk;
#pragma unroll
        for (int r = 0; r < 4; ++r) pk[r] = f2bf(acc[m][n][r] + bn_);
        *(u16x4*)(Out + ((size_t)(b_ * NHEAD + h) * DHEAD + d) * S_LEN + s_) = pk;
      }
    }
  }
}

// ---------------- output projection GEMM ----------------
__global__ __launch_bounds__(256) void gemm_out(
    const u16* __restrict__ Ab, const u16* __restrict__ Wm,
    const float* __restrict__ bias, float* __restrict__ Out) {
  __shared__ u16 As[128 * 32];
  __shared__ u16 Bs[128 * 32];
  const int tid = threadIdx.x;
  const int wave = tid >> 6, lane = tid & 63, g = lane >> 4, c = lane & 15;
  const int wm = wave >> 1, wn = wave & 1;
  const int bm0 = blockIdx.y * 128, bn0 = blockIdx.x * 128;
  const int o = tid * 16;
  const int row = o >> 6;
  const int kp8 = ((o >> 4) & 3) * 8;
  char* lA = (char*)As + wave * 1024;
  char* lB = (char*)Bs + wave * 1024;

  f32x4 acc[4][4];
#pragma unroll
  for (int m = 0; m < 4; ++m)
#pragma unroll
    for (int n = 0; n < 4; ++n) acc[m][n] = (f32x4){0.f, 0.f, 0.f, 0.f};

  for (int k0 = 0; k0 < DMODEL; k0 += 32) {
    __syncthreads();
    GLDS16(Ab + (size_t)(bm0 + row) * DMODEL + k0 + kp8, lA);
    GLDS16(Ab + (size_t)(bm0 + row + 64) * DMODEL + k0 + kp8, lA + 4096);
    GLDS16(Wm + (size_t)(bn0 + row) * DMODEL + k0 + kp8, lB);
    GLDS16(Wm + (size_t)(bn0 + row + 64) * DMODEL + k0 + kp8, lB + 4096);
    __syncthreads();
    bf16x8 af[4], bfr[4];
#pragma unroll
    for (int m = 0; m < 4; ++m)
      af[m] = *(const bf16x8*)(As + (wm * 64 + m * 16 + c) * 32 + g * 8);
#pragma unroll
    for (int n = 0; n < 4; ++n)
      bfr[n] = *(const bf16x8*)(Bs + (wn * 64 + n * 16 + c) * 32 + g * 8);
#pragma unroll
    for (int m = 0; m < 4; ++m)
#pragma unroll
      for (int n = 0; n < 4; ++n)
        acc[m][n] = mfma16(af[m], bfr[n], acc[m][n]);
  }
#pragma unroll
  for (int n = 0; n < 4; ++n) {
    const int coln = bn0 + wn * 64 + n * 16 + c;
    const float bn_ = bias[coln];
#pragma unroll
    for (int m = 0; m < 4; ++m) {
#pragma unroll
      for (int r = 0; r < 4; ++r) {
        const int rowm = bm0 + wm * 64 + m * 16 + g * 4 + r;
        Out[(size_t)rowm * DMODEL + coln] = acc[m][n][r] + bn_;
      }
    }
  }
}

// ---------------- causal flash attention (swapped-operand, in-register softmax) ----------------
// grid 1024: 64 (b,h) x 16 pairs; each block does q-tiles {31-p, p} (33 tile-steps, balanced).
// 4 waves x 16 q-rows. S^T = mfma(K,Q): lane owns q=c's scores for kv = 16t+4g+r,
// in log2 units (log2e/8 folded into Q). Softmax: max3 tree + defer-rescale (T13, THR=8);
// P -> bf16 via +0x8000 round + v_perm pack; PV via wave-local LDS P^T buffer.
__global__ __launch_bounds__(256) void attn_fwd(const u16* __restrict__ Qb,
                                                const u16* __restrict__ Kb,
                                                const u16* __restrict__ VTb,
                                                u16* __restrict__ AOb) {
  __shared__ u16 Kt[64 * 64];       // K tile [kv][d], swizzled chunks
  __shared__ u16 Vt[64 * 64];       // V^T tile [d][kv], swizzled chunks
  __shared__ unsigned Pl[4][16 * 36];  // per-wave P^T: row q=c (stride 36 u32 = 144B)
  const int tid = threadIdx.x;
  const int w = tid >> 6, lane = tid & 63, g = lane >> 4, c = lane & 15;
  const int flat = blockIdx.x;
  const int wg = (flat & 7) * 128 + (flat >> 3);  // XCD-chunked remap (8 heads/XCD)
  const int bh = wg >> 4;
  const int pr = wg & 15;
  const size_t base = (size_t)bh * (S_LEN * DHEAD);  // same stride for K and VT
  const int b_ = bh >> 4, h = bh & 15;
  const int ci0 = w * 64 + lane;    // staging chunk index

#pragma unroll
  for (int pass = 0; pass < 2; ++pass) {
    const int qt = pass ? pr : (31 - pr);
    const int qb = qt * 64;
    const int q = qb + w * 16 + c;   // this lane's q-row
    const bf16x8 qf0 = *(const bf16x8*)(Qb + base + (size_t)q * 64 + g * 8);
    const bf16x8 qf1 = *(const bf16x8*)(Qb + base + (size_t)q * 64 + 32 + g * 8);

    f32x4 oacc[4];
#pragma unroll
    for (int dt = 0; dt < 4; ++dt) oacc[dt] = (f32x4){0.f, 0.f, 0.f, 0.f};
    float m = -30000.f, l = 0.f;

    const int nt = qt + 1;
    for (int kt = 0; kt < nt; ++kt) {
      const int kv0 = kt * 64;
      __syncthreads();  // prev tile's LDS reads done before overwrite
#pragma unroll
      for (int call = 0; call < 2; ++call) {
        const int ci = call * 256 + ci0;
        const int row = ci >> 3;                  // 0..63
        const int colg = (ci & 7) ^ (row & 7);    // inverse-swizzled source chunk
        GLDS16(Kb + base + (size_t)(kv0 + row) * 64 + colg * 8,
               (char*)Kt + (call * 256 + w * 64) * 16);
        GLDS16(VTb + base + (size_t)row * S_LEN + kv0 + colg * 8,
               (char*)Vt + (call * 256 + w * 64) * 16);
      }
      __syncthreads();  // tiles ready (vmcnt drained at barrier)

      // S^T = K Q^T from swizzled LDS: s[t][r] = S[kv=kv0+16t+4g+r][q] (log2 units)
      f32x4 s[4];
#pragma unroll
      for (int t = 0; t < 4; ++t) {
        const int krow = t * 16 + c;
        const char* kbase = (const char*)Kt + krow * 128;
        bf16x8 kf0 = *(const bf16x8*)(kbase + ((g ^ (krow & 7)) * 16));
        bf16x8 kf1 = *(const bf16x8*)(kbase + (((4 + g) ^ (krow & 7)) * 16));
        f32x4 zacc = (f32x4){0.f, 0.f, 0.f, 0.f};
        zacc = mfma16(kf0, qf0, zacc);
        zacc = mfma16(kf1, qf1, zacc);
        s[t] = zacc;
      }
      if (kt == nt - 1) {  // diagonal tile only: causal mask
#pragma unroll
        for (int t = 0; t < 4; ++t)
#pragma unroll
          for (int r = 0; r < 4; ++r)
            if (kv0 + t * 16 + 4 * g + r > q) s[t][r] = -30000.f;
      }
      // row max via max3 tree (16 values) + 2-step cross-g reduce
      const float a0 = fmaxf(fmaxf(s[0][0], s[0][1]), s[0][2]);
      const float a1 = fmaxf(fmaxf(s[0][3], s[1][0]), s[1][1]);
      const float a2 = fmaxf(fmaxf(s[1][2], s[1][3]), s[2][0]);
      const float a3 = fmaxf(fmaxf(s[2][1], s[2][2]), s[2][3]);
      const float a4 = fmaxf(fmaxf(s[3][0], s[3][1]), s[3][2]);
      float pm = fmaxf(fmaxf(fmaxf(a0, a1), a2), fmaxf(fmaxf(a3, a4), s[3][3]));
      pm = fmaxf(pm, __shfl_xor(pm, 16));
      pm = fmaxf(pm, __shfl_xor(pm, 32));
      // defer-rescale (T13): only rescale when some row grew by > 2^8
      if (__any(pm > m + 8.0f)) {
        const float mn = fmaxf(m, pm);
        const float sc = exp2v(m - mn);
        l *= sc;
#pragma unroll
        for (int dt = 0; dt < 4; ++dt) oacc[dt] *= sc;
        m = mn;
      }
      float rs = 0.f;
#pragma unroll
      for (int t = 0; t < 4; ++t) {
        const float p0 = exp2v(s[t][0] - m), p1 = exp2v(s[t][1] - m);
        const float p2 = exp2v(s[t][2] - m), p3 = exp2v(s[t][3] - m);
        rs += (p0 + p1) + (p2 + p3);
        // round-half-up to bf16 and pack pairs with one v_perm each
        const unsigned b0 = __float_as_uint(p0) + 0x8000u;
        const unsigned b1 = __float_as_uint(p1) + 0x8000u;
        const unsigned b2 = __float_as_uint(p2) + 0x8000u;
        const unsigned b3 = __float_as_uint(p3) + 0x8000u;
        u32x2 pk2;
        pk2[0] = __builtin_amdgcn_perm(b1, b0, 0x07060302u);
        pk2[1] = __builtin_amdgcn_perm(b3, b2, 0x07060302u);
        *(u32x2*)&Pl[w][c * 36 + t * 8 + g * 2] = pk2;
      }
      rs += __shfl_xor(rs, 16);
      rs += __shfl_xor(rs, 32);
      l += rs;

      // O^T += V^T P^T : P^T B-frag read back from wave-local LDS
#pragma unroll
      for (int kk = 0; kk < 2; ++kk) {
        const bf16x8 pb = *(const bf16x8*)&Pl[w][c * 36 + kk * 16 + g * 4];
#pragma unroll
        for (int dt = 0; dt < 4; ++dt) {
          const int vrow = dt * 16 + c;
          const bf16x8 vf = *(const bf16x8*)((const char*)Vt + vrow * 128 +
                                             (((kk * 4 + g) ^ (vrow & 7)) * 16));
          oacc[dt] = mfma16(vf, pb, oacc[dt]);
        }
      }
    }
    // epilogue: lane owns O[q][d = dt*16 + 4g + 0..3] -> 8B packed stores
    const float inv = 1.0f / l;
    const size_t rowbase = ((size_t)(b_ * S_LEN + q) * DMODEL) + h * 64;
#pragma unroll
    for (int dt = 0; dt < 4; ++dt) {
      u16x4 pk4;
#pragma unroll
      for (int r = 0; r < 4; ++r) pk4[r] = f2bf(oacc[dt][r] * inv);
      *(u16x4*)(AOb + rowbase + dt * 16 + 4 * g) = pk4;
    }
  }
}

extern "C" void kernel_launch(void* const* d_in, const int* in_sizes, int n_in,
                              void* d_out, int out_size, void* d_ws, size_t ws_size,
                              hipStream_t stream) {
  const float* x  = (const float*)d_in[0];
  const float* Wq = (const float*)d_in[1];
  const float* bq = (const float*)d_in[2];
  const float* Wk = (const float*)d_in[3];
  const float* bk = (const float*)d_in[4];
  const float* Wv = (const float*)d_in[5];
  const float* bv = (const float*)d_in[6];
  const float* Wo = (const float*)d_in[7];
  const float* bo = (const float*)d_in[8];
  float* out = (float*)d_out;
  char* ws = (char*)d_ws;

  const size_t MB = 1024 * 1024;
  u16* xb  = (u16*)(ws);              // 16 MB: x bf16 [8192][1024]
  u16* Wqb = (u16*)(ws + 16 * MB);    // 2 MB each
  u16* Wkb = (u16*)(ws + 18 * MB);
  u16* Wvb = (u16*)(ws + 20 * MB);
  u16* Wob = (u16*)(ws + 22 * MB);
  u16* Qb  = (u16*)(ws + 24 * MB);    // 16 MB (b,h,s,d), pre-scaled (log2 units)
  u16* Kb  = (u16*)(ws + 40 * MB);    // 16 MB (b,h,s,d)
  u16* VTb = (u16*)(ws + 56 * MB);    // 16 MB (b,h,d,s)
  u16* AOb = (u16*)(ws + 72 * MB);    // 16 MB (b,s,h*d)

  castk<<<8192, 256, 0, stream>>>(x, xb, MROWS * DMODEL);
  castk<<<1024, 256, 0, stream>>>(Wq, Wqb, DMODEL * DMODEL);
  castk<<<1024, 256, 0, stream>>>(Wk, Wkb, DMODEL * DMODEL);
  castk<<<1024, 256, 0, stream>>>(Wv, Wvb, DMODEL * DMODEL);

  gemm_qkv<<<dim3(DMODEL / 128, MROWS / 128, 3), 256, 0, stream>>>(
      xb, Wqb, Wkb, Wvb, bq, bk, bv, Qb, Kb, VTb);

  castk<<<1024, 256, 0, stream>>>(Wo, Wob, DMODEL * DMODEL);

  attn_fwd<<<1024, 256, 0, stream>>>(Qb, Kb, VTb, AOb);

  gemm_out<<<dim3(DMODEL / 128, MROWS / 128), 256, 0, stream>>>(AOb, Wob, bo, out);
}

// Round 7
// 187.316 us; speedup vs baseline: 2.3471x; 1.0713x over previous
//
#include <hip/hip_runtime.h>
#include <hip/hip_bf16.h>
#include <math.h>

#define S_LEN 2048
#define DMODEL 1024
#define NHEAD 16
#define DHEAD 64
#define BATCH 4
#define MROWS (BATCH * S_LEN)  // 8192

typedef unsigned short u16;
typedef __attribute__((ext_vector_type(4))) unsigned short u16x4;
typedef __attribute__((ext_vector_type(2))) unsigned u32x2;
typedef __attribute__((ext_vector_type(8))) short bf16x8;
typedef __attribute__((ext_vector_type(4))) float f32x4;

#define GLDS16(g, l)                                              \
  __builtin_amdgcn_global_load_lds(                               \
      (const __attribute__((address_space(1))) void*)(g),         \
      (__attribute__((address_space(3))) void*)(l), 16, 0, 0)

__device__ __forceinline__ u16 f2bf(float f) {
  unsigned u = __float_as_uint(f);
  u += 0x7fff + ((u >> 16) & 1);  // round-to-nearest-even
  return (u16)(u >> 16);
}

__device__ __forceinline__ float exp2v(float x) {  // raw v_exp_f32 (base-2)
  float r;
  asm("v_exp_f32 %0, %1" : "=v"(r) : "v"(x));
  return r;
}

__device__ __forceinline__ f32x4 mfma16(bf16x8 a, bf16x8 b, f32x4 c) {
  return __builtin_amdgcn_mfma_f32_16x16x32_bf16(a, b, c, 0, 0, 0);
}

// ---------------- cast fp32 -> bf16 ----------------
__global__ __launch_bounds__(256) void castk(const float* __restrict__ in,
                                             u16* __restrict__ out, int n) {
  int i = (blockIdx.x * 256 + threadIdx.x) * 4;
  if (i >= n) return;
  f32x4 v = *(const f32x4*)(in + i);
  u16 a0 = f2bf(v[0]), a1 = f2bf(v[1]), a2 = f2bf(v[2]), a3 = f2bf(v[3]);
  out[i + 0] = a0; out[i + 1] = a1; out[i + 2] = a2; out[i + 3] = a3;
}

// 4 weight matrices in one launch (blockIdx.y selects the matrix)
__global__ __launch_bounds__(256) void castw(
    const float* __restrict__ i0, const float* __restrict__ i1,
    const float* __restrict__ i2, const float* __restrict__ i3,
    u16* __restrict__ o0, u16* __restrict__ o1,
    u16* __restrict__ o2, u16* __restrict__ o3) {
  const int m = blockIdx.y;
  const float* in = m == 0 ? i0 : (m == 1 ? i1 : (m == 2 ? i2 : i3));
  u16* out = m == 0 ? o0 : (m == 1 ? o1 : (m == 2 ? o2 : o3));
  int i = (blockIdx.x * 256 + threadIdx.x) * 4;
  f32x4 v = *(const f32x4*)(in + i);
  u16 a0 = f2bf(v[0]), a1 = f2bf(v[1]), a2 = f2bf(v[2]), a3 = f2bf(v[3]);
  out[i + 0] = a0; out[i + 1] = a1; out[i + 2] = a2; out[i + 3] = a3;
}

// ---------------- QKV projection GEMM ----------------
// C[m][n] = sum_k X[m][k] * W[n][k] + bias[n].
// z==0 -> Q (b,h,s,d) pre-scaled by log2(e)/sqrt(64); z==1 -> K; z==2 -> V^T (b,h,d,s).
// 1-D grid 1536, XCD-chunked: XCD i owns m-tiles [8i,8i+8); the 24 (n,z)
// blocks sharing an X panel are XCD-adjacent -> panel fetched once per XCD.
__global__ __launch_bounds__(256) void gemm_qkv(
    const u16* __restrict__ Xb,
    const u16* __restrict__ W0, const u16* __restrict__ W1, const u16* __restrict__ W2,
    const float* __restrict__ b0, const float* __restrict__ b1, const float* __restrict__ b2,
    u16* __restrict__ O0, u16* __restrict__ O1, u16* __restrict__ O2) {
  __shared__ u16 As[128 * 32];
  __shared__ u16 Bs[128 * 32];
  const int flat = blockIdx.x;
  const int xcd = flat & 7, idx = flat >> 3;   // 192 blocks per XCD
  const int ymt = xcd * 8 + idx / 24;          // m-tile 0..63
  const int rem = idx % 24;
  const int xnt = rem & 7;                     // n-tile 0..7
  const int z = rem >> 3;                      // 0..2 (Q/K/V)
  const u16* Wm = z == 0 ? W0 : (z == 1 ? W1 : W2);
  const float* bias = z == 0 ? b0 : (z == 1 ? b1 : b2);
  u16* Out = z == 0 ? O0 : (z == 1 ? O1 : O2);
  // Q pre-scale: (1/sqrt(64)) * log2(e), so attn scores are in log2 units
  const float qs = (z == 0) ? 0.18033688011112042f : 1.0f;
  const int tid = threadIdx.x;
  const int wave = tid >> 6, lane = tid & 63, g = lane >> 4, c = lane & 15;
  const int wm = wave >> 1, wn = wave & 1;
  const int bm0 = ymt * 128, bn0 = xnt * 128;
  const int o = tid * 16;            // flat byte offset in 8KB tile
  const int row = o >> 6;            // 0..63
  const int kp8 = ((o >> 4) & 3) * 8;
  char* lA = (char*)As + wave * 1024;
  char* lB = (char*)Bs + wave * 1024;

  f32x4 acc[4][4];
#pragma unroll
  for (int m = 0; m < 4; ++m)
#pragma unroll
    for (int n = 0; n < 4; ++n) acc[m][n] = (f32x4){0.f, 0.f, 0.f, 0.f};

  for (int k0 = 0; k0 < DMODEL; k0 += 32) {
    __syncthreads();
    GLDS16(Xb + (size_t)(bm0 + row) * DMODEL + k0 + kp8, lA);
    GLDS16(Xb + (size_t)(bm0 + row + 64) * DMODEL + k0 + kp8, lA + 4096);
    GLDS16(Wm + (size_t)(bn0 + row) * DMODEL + k0 + kp8, lB);
    GLDS16(Wm + (size_t)(bn0 + row + 64) * DMODEL + k0 + kp8, lB + 4096);
    __syncthreads();
    bf16x8 af[4], bfr[4];
#pragma unroll
    for (int m = 0; m < 4; ++m)
      af[m] = *(const bf16x8*)(As + (wm * 64 + m * 16 + c) * 32 + g * 8);
#pragma unroll
    for (int n = 0; n < 4; ++n)
      bfr[n] = *(const bf16x8*)(Bs + (wn * 64 + n * 16 + c) * 32 + g * 8);
#pragma unroll
    for (int m = 0; m < 4; ++m)
#pragma unroll
      for (int n = 0; n < 4; ++n)
        acc[m][n] = mfma16(af[m], bfr[n], acc[m][n]);
  }
  if (z < 2) {
    // Q/K: (b,h,s,d) scatter
#pragma unroll
    for (int n = 0; n < 4; ++n) {
      const int coln = bn0 + wn * 64 + n * 16 + c;
      const float bn_ = bias[coln];
      const int h = coln >> 6, d = coln & 63;
#pragma unroll
      for (int m = 0; m < 4; ++m) {
#pragma unroll
        for (int r = 0; r < 4; ++r) {
          const int rowm = bm0 + wm * 64 + m * 16 + g * 4 + r;
          const int b_ = rowm >> 11, s_ = rowm & 2047;
          Out[(((size_t)(b_ * NHEAD + h) * S_LEN + s_) << 6) + d] =
              f2bf((acc[m][n][r] + bn_) * qs);
        }
      }
    }
  } else {
    // V^T: (b,h,d,s) — pack the 4 consecutive-s values into one 8B store
#pragma unroll
    for (int n = 0; n < 4; ++n) {
      const int coln = bn0 + wn * 64 + n * 16 + c;
      const float bn_ = bias[coln];
      const int h = coln >> 6, d = coln & 63;
#pragma unroll
      for (int m = 0; m < 4; ++m) {
        const int row0 = bm0 + wm * 64 + m * 16 + g * 4;
        const int b_ = row0 >> 11, s_ = row0 & 2047;
        u16x4 pk;
#pragma unroll
        for (int r = 0; r < 4; ++r) pk[r] = f2bf(acc[m][n][r] + bn_);
        *(u16x4*)(Out + ((size_t)(b_ * NHEAD + h) * DHEAD + d) * S_LEN + s_) = pk;
      }
    }
  }
}

// ---------------- output projection GEMM ----------------
// 1-D grid 512, XCD-chunked like gemm_qkv (8 m-tiles per XCD).
__global__ __launch_bounds__(256) void gemm_out(
    const u16* __restrict__ Ab, const u16* __restrict__ Wm,
    const float* __restrict__ bias, float* __restrict__ Out) {
  __shared__ u16 As[128 * 32];
  __shared__ u16 Bs[128 * 32];
  const int flat = blockIdx.x;
  const int xcd = flat & 7, idx = flat >> 3;   // 64 blocks per XCD
  const int ymt = xcd * 8 + (idx >> 3);        // m-tile 0..63
  const int xnt = idx & 7;                     // n-tile 0..7
  const int tid = threadIdx.x;
  const int wave = tid >> 6, lane = tid & 63, g = lane >> 4, c = lane & 15;
  const int wm = wave >> 1, wn = wave & 1;
  const int bm0 = ymt * 128, bn0 = xnt * 128;
  const int o = tid * 16;
  const int row = o >> 6;
  const int kp8 = ((o >> 4) & 3) * 8;
  char* lA = (char*)As + wave * 1024;
  char* lB = (char*)Bs + wave * 1024;

  f32x4 acc[4][4];
#pragma unroll
  for (int m = 0; m < 4; ++m)
#pragma unroll
    for (int n = 0; n < 4; ++n) acc[m][n] = (f32x4){0.f, 0.f, 0.f, 0.f};

  for (int k0 = 0; k0 < DMODEL; k0 += 32) {
    __syncthreads();
    GLDS16(Ab + (size_t)(bm0 + row) * DMODEL + k0 + kp8, lA);
    GLDS16(Ab + (size_t)(bm0 + row + 64) * DMODEL + k0 + kp8, lA + 4096);
    GLDS16(Wm + (size_t)(bn0 + row) * DMODEL + k0 + kp8, lB);
    GLDS16(Wm + (size_t)(bn0 + row + 64) * DMODEL + k0 + kp8, lB + 4096);
    __syncthreads();
    bf16x8 af[4], bfr[4];
#pragma unroll
    for (int m = 0; m < 4; ++m)
      af[m] = *(const bf16x8*)(As + (wm * 64 + m * 16 + c) * 32 + g * 8);
#pragma unroll
    for (int n = 0; n < 4; ++n)
      bfr[n] = *(const bf16x8*)(Bs + (wn * 64 + n * 16 + c) * 32 + g * 8);
#pragma unroll
    for (int m = 0; m < 4; ++m)
#pragma unroll
      for (int n = 0; n < 4; ++n)
        acc[m][n] = mfma16(af[m], bfr[n], acc[m][n]);
  }
#pragma unroll
  for (int n = 0; n < 4; ++n) {
    const int coln = bn0 + wn * 64 + n * 16 + c;
    const float bn_ = bias[coln];
#pragma unroll
    for (int m = 0; m < 4; ++m) {
#pragma unroll
      for (int r = 0; r < 4; ++r) {
        const int rowm = bm0 + wm * 64 + m * 16 + g * 4 + r;
        Out[(size_t)rowm * DMODEL + coln] = acc[m][n][r] + bn_;
      }
    }
  }
}

// ---------------- causal flash attention (swapped-operand, in-register softmax) ----------------
// grid 1024: 64 (b,h) x 16 pairs; each block does q-tiles {31-p, p} (33 tile-steps, balanced).
// 4 waves x 16 q-rows. S^T = mfma(K,Q): lane owns q=c's scores for kv = 16t+4g+r,
// in log2 units (log2e/8 folded into Q). Softmax: max3 tree + defer-rescale (T13, THR=8);
// P -> bf16 via +0x8000 round + v_perm pack; PV via wave-local LDS P^T buffer.
__global__ __launch_bounds__(256) void attn_fwd(const u16* __restrict__ Qb,
                                                const u16* __restrict__ Kb,
                                                const u16* __restrict__ VTb,
                                                u16* __restrict__ AOb) {
  __shared__ u16 Kt[64 * 64];       // K tile [kv][d], swizzled chunks
  __shared__ u16 Vt[64 * 64];       // V^T tile [d][kv], swizzled chunks
  __shared__ unsigned Pl[4][16 * 36];  // per-wave P^T: row q=c (stride 36 u32 = 144B)
  const int tid = threadIdx.x;
  const int w = tid >> 6, lane = tid & 63, g = lane >> 4, c = lane & 15;
  const int flat = blockIdx.x;
  const int wg = (flat & 7) * 128 + (flat >> 3);  // XCD-chunked remap (8 heads/XCD)
  const int bh = wg >> 4;
  const int pr = wg & 15;
  const size_t base = (size_t)bh * (S_LEN * DHEAD);  // same stride for K and VT
  const int b_ = bh >> 4, h = bh & 15;
  const int ci0 = w * 64 + lane;    // staging chunk index

#pragma unroll
  for (int pass = 0; pass < 2; ++pass) {
    const int qt = pass ? pr : (31 - pr);
    const int qb = qt * 64;
    const int q = qb + w * 16 + c;   // this lane's q-row
    const bf16x8 qf0 = *(const bf16x8*)(Qb + base + (size_t)q * 64 + g * 8);
    const bf16x8 qf1 = *(const bf16x8*)(Qb + base + (size_t)q * 64 + 32 + g * 8);

    f32x4 oacc[4];
#pragma unroll
    for (int dt = 0; dt < 4; ++dt) oacc[dt] = (f32x4){0.f, 0.f, 0.f, 0.f};
    float m = -30000.f, l = 0.f;

    const int nt = qt + 1;
    for (int kt = 0; kt < nt; ++kt) {
      const int kv0 = kt * 64;
      __syncthreads();  // prev tile's LDS reads done before overwrite
#pragma unroll
      for (int call = 0; call < 2; ++call) {
        const int ci = call * 256 + ci0;
        const int row = ci >> 3;                  // 0..63
        const int colg = (ci & 7) ^ (row & 7);    // inverse-swizzled source chunk
        GLDS16(Kb + base + (size_t)(kv0 + row) * 64 + colg * 8,
               (char*)Kt + (call * 256 + w * 64) * 16);
        GLDS16(VTb + base + (size_t)row * S_LEN + kv0 + colg * 8,
               (char*)Vt + (call * 256 + w * 64) * 16);
      }
      __syncthreads();  // tiles ready (vmcnt drained at barrier)

      // S^T = K Q^T from swizzled LDS: s[t][r] = S[kv=kv0+16t+4g+r][q] (log2 units)
      f32x4 s[4];
#pragma unroll
      for (int t = 0; t < 4; ++t) {
        const int krow = t * 16 + c;
        const char* kbase = (const char*)Kt + krow * 128;
        bf16x8 kf0 = *(const bf16x8*)(kbase + ((g ^ (krow & 7)) * 16));
        bf16x8 kf1 = *(const bf16x8*)(kbase + (((4 + g) ^ (krow & 7)) * 16));
        f32x4 zacc = (f32x4){0.f, 0.f, 0.f, 0.f};
        zacc = mfma16(kf0, qf0, zacc);
        zacc = mfma16(kf1, qf1, zacc);
        s[t] = zacc;
      }
      if (kt == nt - 1) {  // diagonal tile only: causal mask
#pragma unroll
        for (int t = 0; t < 4; ++t)
#pragma unroll
          for (int r = 0; r < 4; ++r)
            if (kv0 + t * 16 + 4 * g + r > q) s[t][r] = -30000.f;
      }
      // row max via max3 tree (16 values) + 2-step cross-g reduce
      const float a0 = fmaxf(fmaxf(s[0][0], s[0][1]), s[0][2]);
      const float a1 = fmaxf(fmaxf(s[0][3], s[1][0]), s[1][1]);
      const float a2 = fmaxf(fmaxf(s[1][2], s[1][3]), s[2][0]);
      const float a3 = fmaxf(fmaxf(s[2][1], s[2][2]), s[2][3]);
      const float a4 = fmaxf(fmaxf(s[3][0], s[3][1]), s[3][2]);
      float pm = fmaxf(fmaxf(fmaxf(a0, a1), a2), fmaxf(fmaxf(a3, a4), s[3][3]));
      pm = fmaxf(pm, __shfl_xor(pm, 16));
      pm = fmaxf(pm, __shfl_xor(pm, 32));
      // defer-rescale (T13): only rescale when some row grew by > 2^8
      if (__any(pm > m + 8.0f)) {
        const float mn = fmaxf(m, pm);
        const float sc = exp2v(m - mn);
        l *= sc;
#pragma unroll
        for (int dt = 0; dt < 4; ++dt) oacc[dt] *= sc;
        m = mn;
      }
      float rs = 0.f;
#pragma unroll
      for (int t = 0; t < 4; ++t) {
        const float p0 = exp2v(s[t][0] - m), p1 = exp2v(s[t][1] - m);
        const float p2 = exp2v(s[t][2] - m), p3 = exp2v(s[t][3] - m);
        rs += (p0 + p1) + (p2 + p3);
        // round-half-up to bf16 and pack pairs with one v_perm each
        const unsigned b0 = __float_as_uint(p0) + 0x8000u;
        const unsigned b1 = __float_as_uint(p1) + 0x8000u;
        const unsigned b2 = __float_as_uint(p2) + 0x8000u;
        const unsigned b3 = __float_as_uint(p3) + 0x8000u;
        u32x2 pk2;
        pk2[0] = __builtin_amdgcn_perm(b1, b0, 0x07060302u);
        pk2[1] = __builtin_amdgcn_perm(b3, b2, 0x07060302u);
        *(u32x2*)&Pl[w][c * 36 + t * 8 + g * 2] = pk2;
      }
      rs += __shfl_xor(rs, 16);
      rs += __shfl_xor(rs, 32);
      l += rs;

      // O^T += V^T P^T : P^T B-frag read back from wave-local LDS
#pragma unroll
      for (int kk = 0; kk < 2; ++kk) {
        const bf16x8 pb = *(const bf16x8*)&Pl[w][c * 36 + kk * 16 + g * 4];
#pragma unroll
        for (int dt = 0; dt < 4; ++dt) {
          const int vrow = dt * 16 + c;
          const bf16x8 vf = *(const bf16x8*)((const char*)Vt + vrow * 128 +
                                             (((kk * 4 + g) ^ (vrow & 7)) * 16));
          oacc[dt] = mfma16(vf, pb, oacc[dt]);
        }
      }
    }
    // epilogue: lane owns O[q][d = dt*16 + 4g + 0..3] -> 8B packed stores
    const float inv = 1.0f / l;
    const size_t rowbase = ((size_t)(b_ * S_LEN + q) * DMODEL) + h * 64;
#pragma unroll
    for (int dt = 0; dt < 4; ++dt) {
      u16x4 pk4;
#pragma unroll
      for (int r = 0; r < 4; ++r) pk4[r] = f2bf(oacc[dt][r] * inv);
      *(u16x4*)(AOb + rowbase + dt * 16 + 4 * g) = pk4;
    }
  }
}

extern "C" void kernel_launch(void* const* d_in, const int* in_sizes, int n_in,
                              void* d_out, int out_size, void* d_ws, size_t ws_size,
                              hipStream_t stream) {
  const float* x  = (const float*)d_in[0];
  const float* Wq = (const float*)d_in[1];
  const float* bq = (const float*)d_in[2];
  const float* Wk = (const float*)d_in[3];
  const float* bk = (const float*)d_in[4];
  const float* Wv = (const float*)d_in[5];
  const float* bv = (const float*)d_in[6];
  const float* Wo = (const float*)d_in[7];
  const float* bo = (const float*)d_in[8];
  float* out = (float*)d_out;
  char* ws = (char*)d_ws;

  const size_t MB = 1024 * 1024;
  u16* xb  = (u16*)(ws);              // 16 MB: x bf16 [8192][1024]
  u16* Wqb = (u16*)(ws + 16 * MB);    // 2 MB each
  u16* Wkb = (u16*)(ws + 18 * MB);
  u16* Wvb = (u16*)(ws + 20 * MB);
  u16* Wob = (u16*)(ws + 22 * MB);
  u16* Qb  = (u16*)(ws + 24 * MB);    // 16 MB (b,h,s,d), pre-scaled (log2 units)
  u16* Kb  = (u16*)(ws + 40 * MB);    // 16 MB (b,h,s,d)
  u16* VTb = (u16*)(ws + 56 * MB);    // 16 MB (b,h,d,s)
  u16* AOb = (u16*)(ws + 72 * MB);    // 16 MB (b,s,h*d)

  castk<<<8192, 256, 0, stream>>>(x, xb, MROWS * DMODEL);
  castw<<<dim3(1024, 4), 256, 0, stream>>>(Wq, Wk, Wv, Wo, Wqb, Wkb, Wvb, Wob);

  gemm_qkv<<<1536, 256, 0, stream>>>(
      xb, Wqb, Wkb, Wvb, bq, bk, bv, Qb, Kb, VTb);

  attn_fwd<<<1024, 256, 0, stream>>>(Qb, Kb, VTb, AOb);

  gemm_out<<<512, 256, 0, stream>>>(AOb, Wob, bo, out);
}

// Round 8
// 179.026 us; speedup vs baseline: 2.4558x; 1.0463x over previous
//
#include <hip/hip_runtime.h>
#include <hip/hip_bf16.h>
#include <math.h>

#define S_LEN 2048
#define DMODEL 1024
#define NHEAD 16
#define DHEAD 64
#define BATCH 4
#define MROWS (BATCH * S_LEN)  // 8192

typedef unsigned short u16;
typedef __attribute__((ext_vector_type(4))) unsigned short u16x4;
typedef __attribute__((ext_vector_type(2))) unsigned u32x2;
typedef __attribute__((ext_vector_type(8))) short bf16x8;
typedef __attribute__((ext_vector_type(4))) float f32x4;

#define GLDS16(g, l)                                              \
  __builtin_amdgcn_global_load_lds(                               \
      (const __attribute__((address_space(1))) void*)(g),         \
      (__attribute__((address_space(3))) void*)(l), 16, 0, 0)

__device__ __forceinline__ u16 f2bf(float f) {
  unsigned u = __float_as_uint(f);
  u += 0x7fff + ((u >> 16) & 1);  // round-to-nearest-even
  return (u16)(u >> 16);
}

__device__ __forceinline__ float exp2v(float x) {  // raw v_exp_f32 (base-2)
  float r;
  asm("v_exp_f32 %0, %1" : "=v"(r) : "v"(x));
  return r;
}

__device__ __forceinline__ f32x4 mfma16(bf16x8 a, bf16x8 b, f32x4 c) {
  return __builtin_amdgcn_mfma_f32_16x16x32_bf16(a, b, c, 0, 0, 0);
}

// ---------------- cast fp32 -> bf16 ----------------
__global__ __launch_bounds__(256) void castk(const float* __restrict__ in,
                                             u16* __restrict__ out, int n) {
  int i = (blockIdx.x * 256 + threadIdx.x) * 4;
  if (i >= n) return;
  f32x4 v = *(const f32x4*)(in + i);
  u16 a0 = f2bf(v[0]), a1 = f2bf(v[1]), a2 = f2bf(v[2]), a3 = f2bf(v[3]);
  out[i + 0] = a0; out[i + 1] = a1; out[i + 2] = a2; out[i + 3] = a3;
}

// 4 weight matrices in one launch (blockIdx.y selects the matrix)
__global__ __launch_bounds__(256) void castw(
    const float* __restrict__ i0, const float* __restrict__ i1,
    const float* __restrict__ i2, const float* __restrict__ i3,
    u16* __restrict__ o0, u16* __restrict__ o1,
    u16* __restrict__ o2, u16* __restrict__ o3) {
  const int m = blockIdx.y;
  const float* in = m == 0 ? i0 : (m == 1 ? i1 : (m == 2 ? i2 : i3));
  u16* out = m == 0 ? o0 : (m == 1 ? o1 : (m == 2 ? o2 : o3));
  int i = (blockIdx.x * 256 + threadIdx.x) * 4;
  f32x4 v = *(const f32x4*)(in + i);
  u16 a0 = f2bf(v[0]), a1 = f2bf(v[1]), a2 = f2bf(v[2]), a3 = f2bf(v[3]);
  out[i + 0] = a0; out[i + 1] = a1; out[i + 2] = a2; out[i + 3] = a3;
}

// ---------------- QKV projection GEMM (BK=64, swizzled LDS) ----------------
// C[m][n] = sum_k X[m][k] * W[n][k] + bias[n].
// z==0 -> Q (b,h,s,d) pre-scaled by log2(e)/sqrt(64); z==1 -> K; z==2 -> V^T (b,h,d,s).
// 1-D grid 1536, XCD-chunked: XCD i owns m-tiles [8i,8i+8).
// LDS tiles [128][64] bf16, chunk-XOR swizzled (chunk ^= row&7) so that
// fragment ds_read_b128 (16 lanes, stride-128B) spreads over 8 chunk slots.
__global__ __launch_bounds__(256) void gemm_qkv(
    const u16* __restrict__ Xb,
    const u16* __restrict__ W0, const u16* __restrict__ W1, const u16* __restrict__ W2,
    const float* __restrict__ b0, const float* __restrict__ b1, const float* __restrict__ b2,
    u16* __restrict__ O0, u16* __restrict__ O1, u16* __restrict__ O2) {
  __shared__ u16 As[128 * 64];
  __shared__ u16 Bs[128 * 64];
  const int flat = blockIdx.x;
  const int xcd = flat & 7, idx = flat >> 3;   // 192 blocks per XCD
  const int ymt = xcd * 8 + idx / 24;          // m-tile 0..63
  const int rem = idx % 24;
  const int xnt = rem & 7;                     // n-tile 0..7
  const int z = rem >> 3;                      // 0..2 (Q/K/V)
  const u16* Wm = z == 0 ? W0 : (z == 1 ? W1 : W2);
  const float* bias = z == 0 ? b0 : (z == 1 ? b1 : b2);
  u16* Out = z == 0 ? O0 : (z == 1 ? O1 : O2);
  // Q pre-scale: (1/sqrt(64)) * log2(e), so attn scores are in log2 units
  const float qs = (z == 0) ? 0.18033688011112042f : 1.0f;
  const int tid = threadIdx.x;
  const int wave = tid >> 6, lane = tid & 63, g = lane >> 4, c = lane & 15;
  const int wm = wave >> 1, wn = wave & 1;
  const int bm0 = ymt * 128, bn0 = xnt * 128;

  f32x4 acc[4][4];
#pragma unroll
  for (int m = 0; m < 4; ++m)
#pragma unroll
    for (int n = 0; n < 4; ++n) acc[m][n] = (f32x4){0.f, 0.f, 0.f, 0.f};

  for (int k0 = 0; k0 < DMODEL; k0 += 64) {
    __syncthreads();
#pragma unroll
    for (int cc = 0; cc < 4; ++cc) {
      const int ci = cc * 256 + tid;            // chunk 0..1023
      const int row = ci >> 3, ch = ci & 7;     // row 0..127
      const int sc = ((ch ^ (row & 7)) << 3);   // inverse-swizzled source col
      GLDS16(Xb + (size_t)(bm0 + row) * DMODEL + k0 + sc,
             (char*)As + (cc * 256 + wave * 64) * 16);
      GLDS16(Wm + (size_t)(bn0 + row) * DMODEL + k0 + sc,
             (char*)Bs + (cc * 256 + wave * 64) * 16);
    }
    __syncthreads();
#pragma unroll
    for (int ks = 0; ks < 2; ++ks) {
      bf16x8 af[4], bfr[4];
#pragma unroll
      for (int m = 0; m < 4; ++m) {
        const int arow = wm * 64 + m * 16 + c;
        af[m] = *(const bf16x8*)((const char*)As + arow * 128 +
                                 (((ks * 4 + g) ^ (arow & 7)) << 4));
      }
#pragma unroll
      for (int n = 0; n < 4; ++n) {
        const int brow = wn * 64 + n * 16 + c;
        bfr[n] = *(const bf16x8*)((const char*)Bs + brow * 128 +
                                  (((ks * 4 + g) ^ (brow & 7)) << 4));
      }
#pragma unroll
      for (int m = 0; m < 4; ++m)
#pragma unroll
        for (int n = 0; n < 4; ++n)
          acc[m][n] = mfma16(af[m], bfr[n], acc[m][n]);
    }
  }
  if (z < 2) {
    // Q/K: (b,h,s,d) scatter
#pragma unroll
    for (int n = 0; n < 4; ++n) {
      const int coln = bn0 + wn * 64 + n * 16 + c;
      const float bn_ = bias[coln];
      const int h = coln >> 6, d = coln & 63;
#pragma unroll
      for (int m = 0; m < 4; ++m) {
#pragma unroll
        for (int r = 0; r < 4; ++r) {
          const int rowm = bm0 + wm * 64 + m * 16 + g * 4 + r;
          const int b_ = rowm >> 11, s_ = rowm & 2047;
          Out[(((size_t)(b_ * NHEAD + h) * S_LEN + s_) << 6) + d] =
              f2bf((acc[m][n][r] + bn_) * qs);
        }
      }
    }
  } else {
    // V^T: (b,h,d,s) — pack the 4 consecutive-s values into one 8B store
#pragma unroll
    for (int n = 0; n < 4; ++n) {
      const int coln = bn0 + wn * 64 + n * 16 + c;
      const float bn_ = bias[coln];
      const int h = coln >> 6, d = coln & 63;
#pragma unroll
      for (int m = 0; m < 4; ++m) {
        const int row0 = bm0 + wm * 64 + m * 16 + g * 4;
        const int b_ = row0 >> 11, s_ = row0 & 2047;
        u16x4 pk;
#pragma unroll
        for (int r = 0; r < 4; ++r) pk[r] = f2bf(acc[m][n][r] + bn_);
        *(u16x4*)(Out + ((size_t)(b_ * NHEAD + h) * DHEAD + d) * S_LEN + s_) = pk;
      }
    }
  }
}

// ---------------- output projection GEMM (BK=64, swizzled LDS) ----------------
// 1-D grid 512, XCD-chunked like gemm_qkv (8 m-tiles per XCD).
__global__ __launch_bounds__(256) void gemm_out(
    const u16* __restrict__ Ab, const u16* __restrict__ Wm,
    const float* __restrict__ bias, float* __restrict__ Out) {
  __shared__ u16 As[128 * 64];
  __shared__ u16 Bs[128 * 64];
  const int flat = blockIdx.x;
  const int xcd = flat & 7, idx = flat >> 3;   // 64 blocks per XCD
  const int ymt = xcd * 8 + (idx >> 3);        // m-tile 0..63
  const int xnt = idx & 7;                     // n-tile 0..7
  const int tid = threadIdx.x;
  const int wave = tid >> 6, lane = tid & 63, g = lane >> 4, c = lane & 15;
  const int wm = wave >> 1, wn = wave & 1;
  const int bm0 = ymt * 128, bn0 = xnt * 128;

  f32x4 acc[4][4];
#pragma unroll
  for (int m = 0; m < 4; ++m)
#pragma unroll
    for (int n = 0; n < 4; ++n) acc[m][n] = (f32x4){0.f, 0.f, 0.f, 0.f};

  for (int k0 = 0; k0 < DMODEL; k0 += 64) {
    __syncthreads();
#pragma unroll
    for (int cc = 0; cc < 4; ++cc) {
      const int ci = cc * 256 + tid;
      const int row = ci >> 3, ch = ci & 7;
      const int sc = ((ch ^ (row & 7)) << 3);
      GLDS16(Ab + (size_t)(bm0 + row) * DMODEL + k0 + sc,
             (char*)As + (cc * 256 + wave * 64) * 16);
      GLDS16(Wm + (size_t)(bn0 + row) * DMODEL + k0 + sc,
             (char*)Bs + (cc * 256 + wave * 64) * 16);
    }
    __syncthreads();
#pragma unroll
    for (int ks = 0; ks < 2; ++ks) {
      bf16x8 af[4], bfr[4];
#pragma unroll
      for (int m = 0; m < 4; ++m) {
        const int arow = wm * 64 + m * 16 + c;
        af[m] = *(const bf16x8*)((const char*)As + arow * 128 +
                                 (((ks * 4 + g) ^ (arow & 7)) << 4));
      }
#pragma unroll
      for (int n = 0; n < 4; ++n) {
        const int brow = wn * 64 + n * 16 + c;
        bfr[n] = *(const bf16x8*)((const char*)Bs + brow * 128 +
                                  (((ks * 4 + g) ^ (brow & 7)) << 4));
      }
#pragma unroll
      for (int m = 0; m < 4; ++m)
#pragma unroll
        for (int n = 0; n < 4; ++n)
          acc[m][n] = mfma16(af[m], bfr[n], acc[m][n]);
    }
  }
#pragma unroll
  for (int n = 0; n < 4; ++n) {
    const int coln = bn0 + wn * 64 + n * 16 + c;
    const float bn_ = bias[coln];
#pragma unroll
    for (int m = 0; m < 4; ++m) {
#pragma unroll
      for (int r = 0; r < 4; ++r) {
        const int rowm = bm0 + wm * 64 + m * 16 + g * 4 + r;
        Out[(size_t)rowm * DMODEL + coln] = acc[m][n][r] + bn_;
      }
    }
  }
}

// ---------------- causal flash attention (swapped-operand, in-register softmax) ----------------
// grid 1024: 64 (b,h) x 16 pairs; each block does q-tiles {31-p, p} (33 tile-steps, balanced).
// 4 waves x 16 q-rows. S^T = mfma(K,Q): lane owns q=c's scores for kv = 16t+4g+r,
// in log2 units (log2e/8 folded into Q). Softmax: max3 tree + defer-rescale (T13, THR=8);
// P -> bf16 via +0x8000 round + v_perm pack; PV via wave-local LDS P^T buffer.
__global__ __launch_bounds__(256) void attn_fwd(const u16* __restrict__ Qb,
                                                const u16* __restrict__ Kb,
                                                const u16* __restrict__ VTb,
                                                u16* __restrict__ AOb) {
  __shared__ u16 Kt[64 * 64];       // K tile [kv][d], swizzled chunks
  __shared__ u16 Vt[64 * 64];       // V^T tile [d][kv], swizzled chunks
  __shared__ unsigned Pl[4][16 * 36];  // per-wave P^T: row q=c (stride 36 u32 = 144B)
  const int tid = threadIdx.x;
  const int w = tid >> 6, lane = tid & 63, g = lane >> 4, c = lane & 15;
  const int flat = blockIdx.x;
  const int wg = (flat & 7) * 128 + (flat >> 3);  // XCD-chunked remap (8 heads/XCD)
  const int bh = wg >> 4;
  const int pr = wg & 15;
  const size_t base = (size_t)bh * (S_LEN * DHEAD);  // same stride for K and VT
  const int b_ = bh >> 4, h = bh & 15;
  const int ci0 = w * 64 + lane;    // staging chunk index

#pragma unroll
  for (int pass = 0; pass < 2; ++pass) {
    const int qt = pass ? pr : (31 - pr);
    const int qb = qt * 64;
    const int q = qb + w * 16 + c;   // this lane's q-row
    const bf16x8 qf0 = *(const bf16x8*)(Qb + base + (size_t)q * 64 + g * 8);
    const bf16x8 qf1 = *(const bf16x8*)(Qb + base + (size_t)q * 64 + 32 + g * 8);

    f32x4 oacc[4];
#pragma unroll
    for (int dt = 0; dt < 4; ++dt) oacc[dt] = (f32x4){0.f, 0.f, 0.f, 0.f};
    float m = -30000.f, l = 0.f;

    const int nt = qt + 1;
    for (int kt = 0; kt < nt; ++kt) {
      const int kv0 = kt * 64;
      __syncthreads();  // prev tile's LDS reads done before overwrite
#pragma unroll
      for (int call = 0; call < 2; ++call) {
        const int ci = call * 256 + ci0;
        const int row = ci >> 3;                  // 0..63
        const int colg = (ci & 7) ^ (row & 7);    // inverse-swizzled source chunk
        GLDS16(Kb + base + (size_t)(kv0 + row) * 64 + colg * 8,
               (char*)Kt + (call * 256 + w * 64) * 16);
        GLDS16(VTb + base + (size_t)row * S_LEN + kv0 + colg * 8,
               (char*)Vt + (call * 256 + w * 64) * 16);
      }
      __syncthreads();  // tiles ready (vmcnt drained at barrier)

      // S^T = K Q^T from swizzled LDS: s[t][r] = S[kv=kv0+16t+4g+r][q] (log2 units)
      f32x4 s[4];
#pragma unroll
      for (int t = 0; t < 4; ++t) {
        const int krow = t * 16 + c;
        const char* kbase = (const char*)Kt + krow * 128;
        bf16x8 kf0 = *(const bf16x8*)(kbase + ((g ^ (krow & 7)) * 16));
        bf16x8 kf1 = *(const bf16x8*)(kbase + (((4 + g) ^ (krow & 7)) * 16));
        f32x4 zacc = (f32x4){0.f, 0.f, 0.f, 0.f};
        zacc = mfma16(kf0, qf0, zacc);
        zacc = mfma16(kf1, qf1, zacc);
        s[t] = zacc;
      }
      if (kt == nt - 1) {  // diagonal tile only: causal mask
#pragma unroll
        for (int t = 0; t < 4; ++t)
#pragma unroll
          for (int r = 0; r < 4; ++r)
            if (kv0 + t * 16 + 4 * g + r > q) s[t][r] = -30000.f;
      }
      // row max via max3 tree (16 values) + 2-step cross-g reduce
      const float a0 = fmaxf(fmaxf(s[0][0], s[0][1]), s[0][2]);
      const float a1 = fmaxf(fmaxf(s[0][3], s[1][0]), s[1][1]);
      const float a2 = fmaxf(fmaxf(s[1][2], s[1][3]), s[2][0]);
      const float a3 = fmaxf(fmaxf(s[2][1], s[2][2]), s[2][3]);
      const float a4 = fmaxf(fmaxf(s[3][0], s[3][1]), s[3][2]);
      float pm = fmaxf(fmaxf(fmaxf(a0, a1), a2), fmaxf(fmaxf(a3, a4), s[3][3]));
      pm = fmaxf(pm, __shfl_xor(pm, 16));
      pm = fmaxf(pm, __shfl_xor(pm, 32));
      // defer-rescale (T13): only rescale when some row grew by > 2^8
      if (__any(pm > m + 8.0f)) {
        const float mn = fmaxf(m, pm);
        const float sc = exp2v(m - mn);
        l *= sc;
#pragma unroll
        for (int dt = 0; dt < 4; ++dt) oacc[dt] *= sc;
        m = mn;
      }
      float rs = 0.f;
#pragma unroll
      for (int t = 0; t < 4; ++t) {
        const float p0 = exp2v(s[t][0] - m), p1 = exp2v(s[t][1] - m);
        const float p2 = exp2v(s[t][2] - m), p3 = exp2v(s[t][3] - m);
        rs += (p0 + p1) + (p2 + p3);
        // round-half-up to bf16 and pack pairs with one v_perm each
        const unsigned b0 = __float_as_uint(p0) + 0x8000u;
        const unsigned b1 = __float_as_uint(p1) + 0x8000u;
        const unsigned b2 = __float_as_uint(p2) + 0x8000u;
        const unsigned b3 = __float_as_uint(p3) + 0x8000u;
        u32x2 pk2;
        pk2[0] = __builtin_amdgcn_perm(b1, b0, 0x07060302u);
        pk2[1] = __builtin_amdgcn_perm(b3, b2, 0x07060302u);
        *(u32x2*)&Pl[w][c * 36 + t * 8 + g * 2] = pk2;
      }
      rs += __shfl_xor(rs, 16);
      rs += __shfl_xor(rs, 32);
      l += rs;

      // O^T += V^T P^T : P^T B-frag read back from wave-local LDS
#pragma unroll
      for (int kk = 0; kk < 2; ++kk) {
        const bf16x8 pb = *(const bf16x8*)&Pl[w][c * 36 + kk * 16 + g * 4];
#pragma unroll
        for (int dt = 0; dt < 4; ++dt) {
          const int vrow = dt * 16 + c;
          const bf16x8 vf = *(const bf16x8*)((const char*)Vt + vrow * 128 +
                                             (((kk * 4 + g) ^ (vrow & 7)) * 16));
          oacc[dt] = mfma16(vf, pb, oacc[dt]);
        }
      }
    }
    // epilogue: lane owns O[q][d = dt*16 + 4g + 0..3] -> 8B packed stores
    const float inv = 1.0f / l;
    const size_t rowbase = ((size_t)(b_ * S_LEN + q) * DMODEL) + h * 64;
#pragma unroll
    for (int dt = 0; dt < 4; ++dt) {
      u16x4 pk4;
#pragma unroll
      for (int r = 0; r < 4; ++r) pk4[r] = f2bf(oacc[dt][r] * inv);
      *(u16x4*)(AOb + rowbase + dt * 16 + 4 * g) = pk4;
    }
  }
}

extern "C" void kernel_launch(void* const* d_in, const int* in_sizes, int n_in,
                              void* d_out, int out_size, void* d_ws, size_t ws_size,
                              hipStream_t stream) {
  const float* x  = (const float*)d_in[0];
  const float* Wq = (const float*)d_in[1];
  const float* bq = (const float*)d_in[2];
  const float* Wk = (const float*)d_in[3];
  const float* bk = (const float*)d_in[4];
  const float* Wv = (const float*)d_in[5];
  const float* bv = (const float*)d_in[6];
  const float* Wo = (const float*)d_in[7];
  const float* bo = (const float*)d_in[8];
  float* out = (float*)d_out;
  char* ws = (char*)d_ws;

  const size_t MB = 1024 * 1024;
  u16* xb  = (u16*)(ws);              // 16 MB: x bf16 [8192][1024]
  u16* Wqb = (u16*)(ws + 16 * MB);    // 2 MB each
  u16* Wkb = (u16*)(ws + 18 * MB);
  u16* Wvb = (u16*)(ws + 20 * MB);
  u16* Wob = (u16*)(ws + 22 * MB);
  u16* Qb  = (u16*)(ws + 24 * MB);    // 16 MB (b,h,s,d), pre-scaled (log2 units)
  u16* Kb  = (u16*)(ws + 40 * MB);    // 16 MB (b,h,s,d)
  u16* VTb = (u16*)(ws + 56 * MB);    // 16 MB (b,h,d,s)
  u16* AOb = (u16*)(ws + 72 * MB);    // 16 MB (b,s,h*d)

  castk<<<8192, 256, 0, stream>>>(x, xb, MROWS * DMODEL);
  castw<<<dim3(1024, 4), 256, 0, stream>>>(Wq, Wk, Wv, Wo, Wqb, Wkb, Wvb, Wob);

  gemm_qkv<<<1536, 256, 0, stream>>>(
      xb, Wqb, Wkb, Wvb, bq, bk, bv, Qb, Kb, VTb);

  attn_fwd<<<1024, 256, 0, stream>>>(Qb, Kb, VTb, AOb);

  gemm_out<<<512, 256, 0, stream>>>(AOb, Wob, bo, out);
}